// Round 15
// baseline (97.939 us; speedup 1.0000x reference)
//
#include <hip/hip_runtime.h>
#include <math.h>

#define BATCH 2048

typedef __attribute__((ext_vector_type(4))) int i32x4;
typedef __attribute__((ext_vector_type(16))) int i32x16;

__device__ __forceinline__ int sdot4(int a, int b, int c) {
    return __builtin_amdgcn_sdot4(a, b, c, false);
}

__device__ __forceinline__ float fsign(float v) {
    return v > 0.f ? 1.f : (v < 0.f ? -1.f : 0.f);
}

// act-LDS swizzle: spread stride-32B pixel vectors across bank quads (T2).
// Involutive, stays within [0, 9248) for this region size.
__device__ __forceinline__ int aswz(int off) {
    return off ^ (((off >> 7) & 7) << 4);
}

// Fused prep: wf1 binarize | w2 pack [tap][half][oc][16] | wf2 binarize
__global__ void prep_all(const float* __restrict__ w2, const float* __restrict__ wf1,
                         const float* __restrict__ wf2,
                         signed char* __restrict__ w2p, signed char* __restrict__ wf1s,
                         signed char* __restrict__ wf2p) {
    int i = blockIdx.x * 256 + threadIdx.x;
    if (i < 2359296) {  // wf1 sign (natural [1024][2304] layout)
        float v = wf1[i];
        wf1s[i] = v > 0.f ? 1 : (v < 0.f ? -1 : 0);
        return;
    }
    i -= 2359296;
    if (i < 51200) {    // w2 [64][32][5][5] -> w2p [25 tap][2 half][64 oc][16 ic]
        int tap = i >> 11;
        int r = i & 2047;
        int half = r >> 10;
        int r2 = r & 1023;
        int oc = r2 >> 4, j = r2 & 15;
        int ic = half * 16 + j;
        float v = w2[(oc * 32 + ic) * 25 + tap];
        w2p[i] = v > 0.f ? 1 : (v < 0.f ? -1 : 0);
        return;
    }
    i -= 51200;
    if (i < 10240) {    // wf2 sign
        float v = wf2[i];
        wf2p[i] = v > 0.f ? 1 : (v < 0.f ? -1 : 0);
    }
}

// K12: fused conv1(+BN+sign+pool) -> LDS act -> conv2 MFMA with B in REGISTERS.
// Block = 2 images, 384 threads (6 waves = 2 N-halves x 3 M-groups).
// LDS 24768 B (act 18496 + xs 6272); no weight LDS at all.
#define K2_IMG_STRIDE 9248          // 17*17*32
#define K2_XOFF 18496               // x staging: 1568 floats (6272 B)
__global__ __launch_bounds__(384, 3) void k12_fused(
        const float* __restrict__ x,
        const float* __restrict__ w1, const float* __restrict__ b1,
        const float* __restrict__ g1, const float* __restrict__ be1,
        const float* __restrict__ m1, const float* __restrict__ v1,
        const signed char* __restrict__ w2p,
        const float* __restrict__ b2, const float* __restrict__ g2,
        const float* __restrict__ be2, const float* __restrict__ m2,
        const float* __restrict__ v2, signed char* __restrict__ act2) {
    __shared__ __align__(16) signed char smem[24768];
    int tid = threadIdx.x;
    int b0 = blockIdx.x * 2;

    int lane = tid & 63, wave = tid >> 6;     // 6 waves
    int nh = wave & 1, mg = wave >> 1;        // N-half, M-group
    int lrow = lane & 31, kh = lane >> 5;
    int oc2 = nh * 32 + lrow;                 // conv2 output channel of this lane

    // ---- phase 0: zero act region, stage x; issue B-register loads early ----
    i32x4* s4 = (i32x4*)smem;
    i32x4 z4 = {0, 0, 0, 0};
    for (int i = tid; i < 1156; i += 384) s4[i] = z4;
    for (int i = tid; i < 392; i += 384)
        ((float4*)(smem + K2_XOFF))[i] = ((const float4*)(x + (size_t)b0 * 784))[i];

    i32x4 bw[25];                             // 25 taps x 16B = 100 VGPRs
#pragma unroll
    for (int tap = 0; tap < 25; ++tap)
        bw[tap] = *(const i32x4*)(w2p + tap * 2048 + kh * 1024 + oc2 * 16);
    __syncthreads();

    // ---- phase 1: conv1 + BN + sign + pool2, swizzled byte writes into act LDS ----
    {
        const float* xs = (const float*)(smem + K2_XOFF);
        int oc = tid & 31, grp = tid >> 5;    // 12 cell-groups
        float sw[9];
#pragma unroll
        for (int i = 0; i < 9; i++) sw[i] = fsign(w1[oc * 9 + i]);
        float bias = b1[oc], mm = m1[oc];
        float sc = g1[oc] / sqrtf(v1[oc] + 1e-5f), bb = be1[oc];
        for (int it = 0; it < 29; it++) {
            int c = grp + 12 * it;            // 0..337 (2 images x 169 cells)
            if (c < 338) {
                int img = (c >= 169) ? 1 : 0;
                int pix = c - img * 169;
                int py = pix / 13, px = pix - py * 13;
                const float* wnd = xs + img * 784 + py * 56 + px * 2;
                float xr[4][4];
#pragma unroll
                for (int dy = 0; dy < 4; dy++) {
                    float2 lo = *(const float2*)(wnd + dy * 28);
                    float2 hi = *(const float2*)(wnd + dy * 28 + 2);
                    xr[dy][0] = lo.x; xr[dy][1] = lo.y;
                    xr[dy][2] = hi.x; xr[dy][3] = hi.y;
                }
                float maxacc = -1e30f;
#pragma unroll
                for (int q = 0; q < 4; q++) {
                    int dyp = q >> 1, dxp = q & 1;
                    float acc = 0.f;
#pragma unroll
                    for (int ky = 0; ky < 3; ky++)
#pragma unroll
                        for (int kx = 0; kx < 3; kx++)
                            acc += xr[dyp + ky][dxp + kx] * sw[ky * 3 + kx];
                    maxacc = fmaxf(maxacc, acc);   // BN monotone (sc>0)
                }
                float bn = (maxacc + bias - mm) * sc + bb;
                int off = ((py + 2) * 17 + (px + 2)) * 32 + oc;
                smem[img * K2_IMG_STRIDE + aswz(off)] = (signed char)fsign(bn);
            }
        }
    }
    __syncthreads();

    // ---- phase 2: MFMA, 3 M-tiles per wave, B from registers ----
    float bias2 = b2[oc2], mm2 = m2[oc2];
    float sc2 = g2[oc2] / sqrtf(v2[oc2] + 1e-5f), bb2 = be2[oc2];
#pragma unroll
    for (int t = 0; t < 3; ++t) {
        int mt = mg * 3 + t;                  // M-tile 0..8
        int m = mt * 32 + lrow;
        int q = m >> 2, j = m & 3;
        int img = q / 36, qq = q - img * 36;
        int oy = 2 * (qq / 6) + (j >> 1);
        int ox = 2 * (qq - (qq / 6) * 6) + (j & 1);
        const signed char* aimg = smem + img * K2_IMG_STRIDE;
        int pixbase = oy * 17 + ox;

        i32x16 acc = {0};
#pragma unroll
        for (int tap = 0; tap < 25; ++tap) {
            int ky = tap / 5, kx = tap - (tap / 5) * 5;
            int off = (pixbase + ky * 17 + kx) * 32 + kh * 16;
            i32x4 a = *(const i32x4*)(aimg + aswz(off));
            acc = __builtin_amdgcn_mfma_i32_32x32x32_i8(a, bw[tap], acc, 0, 0, 0);
        }
        // epilogue: pool quad lives in reg quads of this lane
#pragma unroll
        for (int g = 0; g < 4; g++) {
            int qo = mt * 8 + kh + 2 * g;     // 0..71 pool cell (2 images)
            int imo = qo / 36, qqo = qo - imo * 36;
            float best = -2.f;
#pragma unroll
            for (int jj = 0; jj < 4; jj++) {
                float z = (float)acc[g * 4 + jj] + bias2;
                float bn = (z - mm2) * sc2 + bb2;
                best = fmaxf(best, fsign(bn));
            }
            act2[((size_t)(b0 + imo) * 64 + oc2) * 36 + qqo] = (signed char)best;
        }
    }
}

// K3: fc1 as LDS-tiled MFMA i8 GEMM 2048x1024x2304. (unchanged)
#define K3A_SEG 2064                // 128*16 + 16 pad
#define K3B_SEG 1040                // 64*16 + 16 pad
#define K3_BOFF 16512               // 8 * 2064
__global__ __launch_bounds__(256) void k3_mfma(
        const signed char* __restrict__ act2, const signed char* __restrict__ wf1s,
        const float* __restrict__ bf1, const float* __restrict__ gf1,
        const float* __restrict__ bef1, const float* __restrict__ mf1,
        const float* __restrict__ vf1, signed char* __restrict__ act3) {
    __shared__ __align__(16) signed char s[K3_BOFF + 8 * K3B_SEG];  // 24832
    int tid = threadIdx.x;
    int bid = blockIdx.x;
    int tn = bid & 15, tm = bid >> 4;

    const signed char* Ab = act2 + (size_t)tm * 128 * 2304;
    const signed char* Bb = wf1s + (size_t)tn * 64 * 2304;
    size_t gA[4]; int lwA[4];
#pragma unroll
    for (int i = 0; i < 4; i++) {
        int e = tid + 256 * i, row = e >> 3, sg = (e + row) & 7;
        gA[i] = (size_t)row * 2304 + sg * 16;
        lwA[i] = sg * K3A_SEG + row * 16;
    }
    size_t gB[2]; int lwB[2];
#pragma unroll
    for (int i = 0; i < 2; i++) {
        int e = tid + 256 * i, row = e >> 3, sg = (e + row) & 7;
        gB[i] = (size_t)row * 2304 + sg * 16;
        lwB[i] = K3_BOFF + sg * K3B_SEG + row * 16;
    }

    i32x4 ra[4], rb[2];
#pragma unroll
    for (int i = 0; i < 4; i++) ra[i] = *(const i32x4*)(Ab + gA[i]);
#pragma unroll
    for (int i = 0; i < 2; i++) rb[i] = *(const i32x4*)(Bb + gB[i]);

    int l = tid & 63, wid = tid >> 6;
    int lrow = l & 31, kh = l >> 5;
    int raddrA = kh * K3A_SEG + (wid * 32 + lrow) * 16;
    int raddrB0 = K3_BOFF + kh * K3B_SEG + lrow * 16;
    int raddrB1 = raddrB0 + 32 * 16;

    i32x16 acc0 = {0};
    i32x16 acc1 = {0};
    for (int t = 0; t < 18; ++t) {
        if (t) __syncthreads();
#pragma unroll
        for (int i = 0; i < 4; i++) *(i32x4*)(s + lwA[i]) = ra[i];
#pragma unroll
        for (int i = 0; i < 2; i++) *(i32x4*)(s + lwB[i]) = rb[i];
        if (t < 17) {
            size_t ko = (size_t)(t + 1) * 128;
#pragma unroll
            for (int i = 0; i < 4; i++) ra[i] = *(const i32x4*)(Ab + gA[i] + ko);
#pragma unroll
            for (int i = 0; i < 2; i++) rb[i] = *(const i32x4*)(Bb + gB[i] + ko);
        }
        __syncthreads();
#pragma unroll
        for (int ks = 0; ks < 4; ++ks) {
            i32x4 a  = *(const i32x4*)(s + raddrA + ks * 2 * K3A_SEG);
            i32x4 b0 = *(const i32x4*)(s + raddrB0 + ks * 2 * K3B_SEG);
            i32x4 b1 = *(const i32x4*)(s + raddrB1 + ks * 2 * K3B_SEG);
            acc0 = __builtin_amdgcn_mfma_i32_32x32x32_i8(a, b0, acc0, 0, 0, 0);
            acc1 = __builtin_amdgcn_mfma_i32_32x32x32_i8(a, b1, acc1, 0, 0, 0);
        }
    }

    int col0 = tn * 64 + lrow;
    int col1 = col0 + 32;
    float bi0 = bf1[col0], m0 = mf1[col0];
    float sc0 = gf1[col0] / sqrtf(vf1[col0] + 1e-5f), bb0 = bef1[col0];
    float bi1 = bf1[col1], m1 = mf1[col1];
    float sc1 = gf1[col1] / sqrtf(vf1[col1] + 1e-5f), bb1 = bef1[col1];
#pragma unroll
    for (int r = 0; r < 16; r++) {
        int row = tm * 128 + wid * 32 + (r & 3) + 8 * (r >> 2) + 4 * kh;
        float bn0 = ((float)acc0[r] + bi0 - m0) * sc0 + bb0;
        float bn1 = ((float)acc1[r] + bi1 - m1) * sc1 + bb1;
        act3[(size_t)row * 1024 + col0] = (signed char)fsign(bn0);
        act3[(size_t)row * 1024 + col1] = (signed char)fsign(bn1);
    }
}

// K4: fc2 (1024->10) + bias + BN + log_softmax. One wave per image. (unchanged)
__global__ void k4_fc2(const signed char* __restrict__ act3, const signed char* __restrict__ swf2,
                       const float* __restrict__ bf2, const float* __restrict__ gf2,
                       const float* __restrict__ bef2, const float* __restrict__ mf2,
                       const float* __restrict__ vf2, float* __restrict__ out) {
    int wid = (blockIdx.x * 256 + threadIdx.x) >> 6;
    int lane = threadIdx.x & 63;
    if (wid >= BATCH) return;
    const int* hd = (const int*)act3 + (size_t)wid * 256;
    const int* wd = (const int*)swf2;
    int acc[10];
#pragma unroll
    for (int o = 0; o < 10; o++) acc[o] = 0;
#pragma unroll
    for (int i = 0; i < 4; i++) {
        int k4 = i * 64 + lane;
        int hv = hd[k4];
#pragma unroll
        for (int o = 0; o < 10; o++)
            acc[o] = sdot4(hv, wd[o * 256 + k4], acc[o]);
    }
#pragma unroll
    for (int o = 0; o < 10; o++)
#pragma unroll
        for (int s = 32; s > 0; s >>= 1) acc[o] += __shfl_xor(acc[o], s);
    if (lane == 0) {
        float logit[10];
        float mx = -1e30f;
#pragma unroll
        for (int o = 0; o < 10; o++) {
            float z = (float)acc[o] + bf2[o];
            float bn = (z - mf2[o]) * (gf2[o] / sqrtf(vf2[o] + 1e-5f)) + bef2[o];
            logit[o] = bn;
            mx = fmaxf(mx, bn);
        }
        float s = 0.f;
#pragma unroll
        for (int o = 0; o < 10; o++) s += expf(logit[o] - mx);
        float lse = mx + logf(s);
#pragma unroll
        for (int o = 0; o < 10; o++) out[(size_t)wid * 10 + o] = logit[o] - lse;
    }
}

extern "C" void kernel_launch(void* const* d_in, const int* in_sizes, int n_in,
                              void* d_out, int out_size, void* d_ws, size_t ws_size,
                              hipStream_t stream) {
    const float* x   = (const float*)d_in[0];
    const float* w1  = (const float*)d_in[1];
    const float* b1  = (const float*)d_in[2];
    const float* g1  = (const float*)d_in[3];
    const float* be1 = (const float*)d_in[4];
    const float* m1  = (const float*)d_in[5];
    const float* v1  = (const float*)d_in[6];
    const float* w2  = (const float*)d_in[7];
    const float* b2  = (const float*)d_in[8];
    const float* g2  = (const float*)d_in[9];
    const float* be2 = (const float*)d_in[10];
    const float* m2  = (const float*)d_in[11];
    const float* v2  = (const float*)d_in[12];
    const float* wf1 = (const float*)d_in[13];
    const float* bf1 = (const float*)d_in[14];
    const float* gf1 = (const float*)d_in[15];
    const float* bef1= (const float*)d_in[16];
    const float* mf1 = (const float*)d_in[17];
    const float* vf1 = (const float*)d_in[18];
    const float* wf2 = (const float*)d_in[19];
    const float* bf2 = (const float*)d_in[20];
    const float* gf2 = (const float*)d_in[21];
    const float* bef2= (const float*)d_in[22];
    const float* mf2 = (const float*)d_in[23];
    const float* vf2 = (const float*)d_in[24];
    float* out = (float*)d_out;

    // ws layout (all int8)
    char* ws = (char*)d_ws;
    signed char* act2 = (signed char*)ws;                  // 2048*2304     =  4,718,592
    signed char* act3 = act2 + 4718592;                    // 2048*1024     =  2,097,152
    signed char* w2p  = act3 + 2097152;                    // 25*2*64*16    =     51,200
    signed char* wf1s = w2p + 51200;                       // 1024*2304     =  2,359,296
    signed char* wf2p = wf1s + 2359296;                    // 10*1024       =     10,240

    // prep: 2,359,296 + 51,200 + 10,240 = 2,420,736 elems -> 9456 blocks exact
    prep_all<<<9456, 256, 0, stream>>>(w2, wf1, wf2, w2p, wf1s, wf2p);

    k12_fused<<<1024, 384, 0, stream>>>(x, w1, b1, g1, be1, m1, v1,
                                        w2p, b2, g2, be2, m2, v2, act2);

    k3_mfma<<<256, 256, 0, stream>>>(act2, wf1s, bf1, gf1, bef1, mf1, vf1, act3);

    k4_fc2<<<512, 256, 0, stream>>>(act3, wf2p, bf2, gf2, bef2, mf2, vf2, out);
}

// Round 16
// 95.211 us; speedup vs baseline: 1.0287x; 1.0287x over previous
//
#include <hip/hip_runtime.h>
#include <math.h>

#define BATCH 2048

typedef __attribute__((ext_vector_type(4))) int i32x4;
typedef __attribute__((ext_vector_type(16))) int i32x16;

__device__ __forceinline__ int sdot4(int a, int b, int c) {
    return __builtin_amdgcn_sdot4(a, b, c, false);
}

__device__ __forceinline__ float fsign(float v) {
    return v > 0.f ? 1.f : (v < 0.f ? -1.f : 0.f);
}

// act-LDS swizzle: spread stride-32B pixel vectors across bank quads (T2).
__device__ __forceinline__ int aswz(int off) {
    return off ^ (((off >> 7) & 7) << 4);
}

// Fused prep: wf1 binarize | w2 pack [tap][half][oc][16] | wf2 binarize
__global__ void prep_all(const float* __restrict__ w2, const float* __restrict__ wf1,
                         const float* __restrict__ wf2,
                         signed char* __restrict__ w2p, signed char* __restrict__ wf1s,
                         signed char* __restrict__ wf2p) {
    int i = blockIdx.x * 256 + threadIdx.x;
    if (i < 2359296) {  // wf1 sign (natural [1024][2304] layout)
        float v = wf1[i];
        wf1s[i] = v > 0.f ? 1 : (v < 0.f ? -1 : 0);
        return;
    }
    i -= 2359296;
    if (i < 51200) {    // w2 [64][32][5][5] -> w2p [25 tap][2 half][64 oc][16 ic]
        int tap = i >> 11;
        int r = i & 2047;
        int half = r >> 10;
        int r2 = r & 1023;
        int oc = r2 >> 4, j = r2 & 15;
        int ic = half * 16 + j;
        float v = w2[(oc * 32 + ic) * 25 + tap];
        w2p[i] = v > 0.f ? 1 : (v < 0.f ? -1 : 0);
        return;
    }
    i -= 51200;
    if (i < 10240) {    // wf2 sign
        float v = wf2[i];
        wf2p[i] = v > 0.f ? 1 : (v < 0.f ? -1 : 0);
    }
}

// K12: fused conv1(+BN+sign+pool) -> LDS act -> conv2 MFMA with B in REGISTERS.
// Block = 2 images, 384 threads (6 waves = 2 N-halves x 3 M-groups).
// NOTE: no min-wave clamp in launch_bounds — bw[25] needs ~100 VGPRs resident.
#define K2_IMG_STRIDE 9248          // 17*17*32
#define K2_XOFF 18496               // x staging: 1568 floats (6272 B)
__global__ __launch_bounds__(384) void k12_fused(
        const float* __restrict__ x,
        const float* __restrict__ w1, const float* __restrict__ b1,
        const float* __restrict__ g1, const float* __restrict__ be1,
        const float* __restrict__ m1, const float* __restrict__ v1,
        const signed char* __restrict__ w2p,
        const float* __restrict__ b2, const float* __restrict__ g2,
        const float* __restrict__ be2, const float* __restrict__ m2,
        const float* __restrict__ v2, signed char* __restrict__ act2) {
    __shared__ __align__(16) signed char smem[24768];
    int tid = threadIdx.x;
    int b0 = blockIdx.x * 2;

    int lane = tid & 63, wave = tid >> 6;     // 6 waves
    int nh = wave & 1, mg = wave >> 1;        // N-half, M-group
    int lrow = lane & 31, kh = lane >> 5;
    int oc2 = nh * 32 + lrow;                 // conv2 output channel of this lane

    // ---- phase 0: zero act region, stage x ----
    i32x4* s4 = (i32x4*)smem;
    i32x4 z4 = {0, 0, 0, 0};
    for (int i = tid; i < 1156; i += 384) s4[i] = z4;
    for (int i = tid; i < 392; i += 384)
        ((float4*)(smem + K2_XOFF))[i] = ((const float4*)(x + (size_t)b0 * 784))[i];
    __syncthreads();

    // ---- phase 1: conv1 + BN + sign + pool2, swizzled byte writes into act LDS ----
    {
        const float* xs = (const float*)(smem + K2_XOFF);
        int oc = tid & 31, grp = tid >> 5;    // 12 cell-groups
        float sw[9];
#pragma unroll
        for (int i = 0; i < 9; i++) sw[i] = fsign(w1[oc * 9 + i]);
        float bias = b1[oc], mm = m1[oc];
        float sc = g1[oc] / sqrtf(v1[oc] + 1e-5f), bb = be1[oc];
        for (int it = 0; it < 29; it++) {
            int c = grp + 12 * it;            // 0..337 (2 images x 169 cells)
            if (c < 338) {
                int img = (c >= 169) ? 1 : 0;
                int pix = c - img * 169;
                int py = pix / 13, px = pix - py * 13;
                const float* wnd = xs + img * 784 + py * 56 + px * 2;
                float xr[4][4];
#pragma unroll
                for (int dy = 0; dy < 4; dy++) {
                    float2 lo = *(const float2*)(wnd + dy * 28);
                    float2 hi = *(const float2*)(wnd + dy * 28 + 2);
                    xr[dy][0] = lo.x; xr[dy][1] = lo.y;
                    xr[dy][2] = hi.x; xr[dy][3] = hi.y;
                }
                float maxacc = -1e30f;
#pragma unroll
                for (int q = 0; q < 4; q++) {
                    int dyp = q >> 1, dxp = q & 1;
                    float acc = 0.f;
#pragma unroll
                    for (int ky = 0; ky < 3; ky++)
#pragma unroll
                        for (int kx = 0; kx < 3; kx++)
                            acc += xr[dyp + ky][dxp + kx] * sw[ky * 3 + kx];
                    maxacc = fmaxf(maxacc, acc);   // BN monotone (sc>0)
                }
                float bn = (maxacc + bias - mm) * sc + bb;
                int off = ((py + 2) * 17 + (px + 2)) * 32 + oc;
                smem[img * K2_IMG_STRIDE + aswz(off)] = (signed char)fsign(bn);
            }
        }
    }

    // B-register loads issued here: latency hides in the barrier wait below,
    // and bw's 100-VGPR live range doesn't overlap conv1's working set.
    i32x4 bw[25];                             // 25 taps x 16B
#pragma unroll
    for (int tap = 0; tap < 25; ++tap)
        bw[tap] = *(const i32x4*)(w2p + tap * 2048 + kh * 1024 + oc2 * 16);
    __syncthreads();

    // ---- phase 2: MFMA, 3 M-tiles per wave, B from registers ----
    float bias2 = b2[oc2], mm2 = m2[oc2];
    float sc2 = g2[oc2] / sqrtf(v2[oc2] + 1e-5f), bb2 = be2[oc2];
#pragma unroll
    for (int t = 0; t < 3; ++t) {
        int mt = mg * 3 + t;                  // M-tile 0..8
        int m = mt * 32 + lrow;
        int q = m >> 2, j = m & 3;
        int img = q / 36, qq = q - img * 36;
        int oy = 2 * (qq / 6) + (j >> 1);
        int ox = 2 * (qq - (qq / 6) * 6) + (j & 1);
        const signed char* aimg = smem + img * K2_IMG_STRIDE;
        int pixbase = oy * 17 + ox;

        i32x16 acc = {0};
#pragma unroll
        for (int tap = 0; tap < 25; ++tap) {
            int ky = tap / 5, kx = tap - (tap / 5) * 5;
            int off = (pixbase + ky * 17 + kx) * 32 + kh * 16;
            i32x4 a = *(const i32x4*)(aimg + aswz(off));
            acc = __builtin_amdgcn_mfma_i32_32x32x32_i8(a, bw[tap], acc, 0, 0, 0);
        }
        // epilogue: pool quad lives in reg quads of this lane
#pragma unroll
        for (int g = 0; g < 4; g++) {
            int qo = mt * 8 + kh + 2 * g;     // 0..71 pool cell (2 images)
            int imo = qo / 36, qqo = qo - imo * 36;
            float best = -2.f;
#pragma unroll
            for (int jj = 0; jj < 4; jj++) {
                float z = (float)acc[g * 4 + jj] + bias2;
                float bn = (z - mm2) * sc2 + bb2;
                best = fmaxf(best, fsign(bn));
            }
            act2[((size_t)(b0 + imo) * 64 + oc2) * 36 + qqo] = (signed char)best;
        }
    }
}

// K3: fc1 as LDS-tiled MFMA i8 GEMM 2048x1024x2304. (unchanged)
#define K3A_SEG 2064                // 128*16 + 16 pad
#define K3B_SEG 1040                // 64*16 + 16 pad
#define K3_BOFF 16512               // 8 * 2064
__global__ __launch_bounds__(256) void k3_mfma(
        const signed char* __restrict__ act2, const signed char* __restrict__ wf1s,
        const float* __restrict__ bf1, const float* __restrict__ gf1,
        const float* __restrict__ bef1, const float* __restrict__ mf1,
        const float* __restrict__ vf1, signed char* __restrict__ act3) {
    __shared__ __align__(16) signed char s[K3_BOFF + 8 * K3B_SEG];  // 24832
    int tid = threadIdx.x;
    int bid = blockIdx.x;
    int tn = bid & 15, tm = bid >> 4;

    const signed char* Ab = act2 + (size_t)tm * 128 * 2304;
    const signed char* Bb = wf1s + (size_t)tn * 64 * 2304;
    size_t gA[4]; int lwA[4];
#pragma unroll
    for (int i = 0; i < 4; i++) {
        int e = tid + 256 * i, row = e >> 3, sg = (e + row) & 7;
        gA[i] = (size_t)row * 2304 + sg * 16;
        lwA[i] = sg * K3A_SEG + row * 16;
    }
    size_t gB[2]; int lwB[2];
#pragma unroll
    for (int i = 0; i < 2; i++) {
        int e = tid + 256 * i, row = e >> 3, sg = (e + row) & 7;
        gB[i] = (size_t)row * 2304 + sg * 16;
        lwB[i] = K3_BOFF + sg * K3B_SEG + row * 16;
    }

    i32x4 ra[4], rb[2];
#pragma unroll
    for (int i = 0; i < 4; i++) ra[i] = *(const i32x4*)(Ab + gA[i]);
#pragma unroll
    for (int i = 0; i < 2; i++) rb[i] = *(const i32x4*)(Bb + gB[i]);

    int l = tid & 63, wid = tid >> 6;
    int lrow = l & 31, kh = l >> 5;
    int raddrA = kh * K3A_SEG + (wid * 32 + lrow) * 16;
    int raddrB0 = K3_BOFF + kh * K3B_SEG + lrow * 16;
    int raddrB1 = raddrB0 + 32 * 16;

    i32x16 acc0 = {0};
    i32x16 acc1 = {0};
    for (int t = 0; t < 18; ++t) {
        if (t) __syncthreads();
#pragma unroll
        for (int i = 0; i < 4; i++) *(i32x4*)(s + lwA[i]) = ra[i];
#pragma unroll
        for (int i = 0; i < 2; i++) *(i32x4*)(s + lwB[i]) = rb[i];
        if (t < 17) {
            size_t ko = (size_t)(t + 1) * 128;
#pragma unroll
            for (int i = 0; i < 4; i++) ra[i] = *(const i32x4*)(Ab + gA[i] + ko);
#pragma unroll
            for (int i = 0; i < 2; i++) rb[i] = *(const i32x4*)(Bb + gB[i] + ko);
        }
        __syncthreads();
#pragma unroll
        for (int ks = 0; ks < 4; ++ks) {
            i32x4 a  = *(const i32x4*)(s + raddrA + ks * 2 * K3A_SEG);
            i32x4 b0 = *(const i32x4*)(s + raddrB0 + ks * 2 * K3B_SEG);
            i32x4 b1 = *(const i32x4*)(s + raddrB1 + ks * 2 * K3B_SEG);
            acc0 = __builtin_amdgcn_mfma_i32_32x32x32_i8(a, b0, acc0, 0, 0, 0);
            acc1 = __builtin_amdgcn_mfma_i32_32x32x32_i8(a, b1, acc1, 0, 0, 0);
        }
    }

    int col0 = tn * 64 + lrow;
    int col1 = col0 + 32;
    float bi0 = bf1[col0], m0 = mf1[col0];
    float sc0 = gf1[col0] / sqrtf(vf1[col0] + 1e-5f), bb0 = bef1[col0];
    float bi1 = bf1[col1], m1 = mf1[col1];
    float sc1 = gf1[col1] / sqrtf(vf1[col1] + 1e-5f), bb1 = bef1[col1];
#pragma unroll
    for (int r = 0; r < 16; r++) {
        int row = tm * 128 + wid * 32 + (r & 3) + 8 * (r >> 2) + 4 * kh;
        float bn0 = ((float)acc0[r] + bi0 - m0) * sc0 + bb0;
        float bn1 = ((float)acc1[r] + bi1 - m1) * sc1 + bb1;
        act3[(size_t)row * 1024 + col0] = (signed char)fsign(bn0);
        act3[(size_t)row * 1024 + col1] = (signed char)fsign(bn1);
    }
}

// K4: fc2 (1024->10) + bias + BN + log_softmax. One wave per image. (unchanged)
__global__ void k4_fc2(const signed char* __restrict__ act3, const signed char* __restrict__ swf2,
                       const float* __restrict__ bf2, const float* __restrict__ gf2,
                       const float* __restrict__ bef2, const float* __restrict__ mf2,
                       const float* __restrict__ vf2, float* __restrict__ out) {
    int wid = (blockIdx.x * 256 + threadIdx.x) >> 6;
    int lane = threadIdx.x & 63;
    if (wid >= BATCH) return;
    const int* hd = (const int*)act3 + (size_t)wid * 256;
    const int* wd = (const int*)swf2;
    int acc[10];
#pragma unroll
    for (int o = 0; o < 10; o++) acc[o] = 0;
#pragma unroll
    for (int i = 0; i < 4; i++) {
        int k4 = i * 64 + lane;
        int hv = hd[k4];
#pragma unroll
        for (int o = 0; o < 10; o++)
            acc[o] = sdot4(hv, wd[o * 256 + k4], acc[o]);
    }
#pragma unroll
    for (int o = 0; o < 10; o++)
#pragma unroll
        for (int s = 32; s > 0; s >>= 1) acc[o] += __shfl_xor(acc[o], s);
    if (lane == 0) {
        float logit[10];
        float mx = -1e30f;
#pragma unroll
        for (int o = 0; o < 10; o++) {
            float z = (float)acc[o] + bf2[o];
            float bn = (z - mf2[o]) * (gf2[o] / sqrtf(vf2[o] + 1e-5f)) + bef2[o];
            logit[o] = bn;
            mx = fmaxf(mx, bn);
        }
        float s = 0.f;
#pragma unroll
        for (int o = 0; o < 10; o++) s += expf(logit[o] - mx);
        float lse = mx + logf(s);
#pragma unroll
        for (int o = 0; o < 10; o++) out[(size_t)wid * 10 + o] = logit[o] - lse;
    }
}

extern "C" void kernel_launch(void* const* d_in, const int* in_sizes, int n_in,
                              void* d_out, int out_size, void* d_ws, size_t ws_size,
                              hipStream_t stream) {
    const float* x   = (const float*)d_in[0];
    const float* w1  = (const float*)d_in[1];
    const float* b1  = (const float*)d_in[2];
    const float* g1  = (const float*)d_in[3];
    const float* be1 = (const float*)d_in[4];
    const float* m1  = (const float*)d_in[5];
    const float* v1  = (const float*)d_in[6];
    const float* w2  = (const float*)d_in[7];
    const float* b2  = (const float*)d_in[8];
    const float* g2  = (const float*)d_in[9];
    const float* be2 = (const float*)d_in[10];
    const float* m2  = (const float*)d_in[11];
    const float* v2  = (const float*)d_in[12];
    const float* wf1 = (const float*)d_in[13];
    const float* bf1 = (const float*)d_in[14];
    const float* gf1 = (const float*)d_in[15];
    const float* bef1= (const float*)d_in[16];
    const float* mf1 = (const float*)d_in[17];
    const float* vf1 = (const float*)d_in[18];
    const float* wf2 = (const float*)d_in[19];
    const float* bf2 = (const float*)d_in[20];
    const float* gf2 = (const float*)d_in[21];
    const float* bef2= (const float*)d_in[22];
    const float* mf2 = (const float*)d_in[23];
    const float* vf2 = (const float*)d_in[24];
    float* out = (float*)d_out;

    // ws layout (all int8)
    char* ws = (char*)d_ws;
    signed char* act2 = (signed char*)ws;                  // 2048*2304     =  4,718,592
    signed char* act3 = act2 + 4718592;                    // 2048*1024     =  2,097,152
    signed char* w2p  = act3 + 2097152;                    // 25*2*64*16    =     51,200
    signed char* wf1s = w2p + 51200;                       // 1024*2304     =  2,359,296
    signed char* wf2p = wf1s + 2359296;                    // 10*1024       =     10,240

    // prep: 2,359,296 + 51,200 + 10,240 = 2,420,736 elems -> 9456 blocks exact
    prep_all<<<9456, 256, 0, stream>>>(w2, wf1, wf2, w2p, wf1s, wf2p);

    k12_fused<<<1024, 384, 0, stream>>>(x, w1, b1, g1, be1, m1, v1,
                                        w2p, b2, g2, be2, m2, v2, act2);

    k3_mfma<<<256, 256, 0, stream>>>(act2, wf1s, bf1, gf1, bef1, mf1, vf1, act3);

    k4_fc2<<<512, 256, 0, stream>>>(act3, wf2p, bf2, gf2, bef2, mf2, vf2, out);
}

// Round 17
// 90.056 us; speedup vs baseline: 1.0875x; 1.0572x over previous
//
#include <hip/hip_runtime.h>
#include <math.h>

#define BATCH 2048

typedef __attribute__((ext_vector_type(4))) int i32x4;
typedef __attribute__((ext_vector_type(16))) int i32x16;

__device__ __forceinline__ int sdot4(int a, int b, int c) {
    return __builtin_amdgcn_sdot4(a, b, c, false);
}

__device__ __forceinline__ float fsign(float v) {
    return v > 0.f ? 1.f : (v < 0.f ? -1.f : 0.f);
}

// act-LDS swizzle: spread stride-32B pixel vectors across bank quads (T2).
// Bijective within [0, 9248); keeps 16B chunks intact.
__device__ __forceinline__ int aswz(int off) {
    return off ^ (((off >> 7) & 7) << 4);
}

// Fused prep: wf1 binarize | w2 pack [tap][half][oc][16] | wf2 binarize
__global__ void prep_all(const float* __restrict__ w2, const float* __restrict__ wf1,
                         const float* __restrict__ wf2,
                         signed char* __restrict__ w2p, signed char* __restrict__ wf1s,
                         signed char* __restrict__ wf2p) {
    int i = blockIdx.x * 256 + threadIdx.x;
    if (i < 2359296) {  // wf1 sign (natural [1024][2304] layout)
        float v = wf1[i];
        wf1s[i] = v > 0.f ? 1 : (v < 0.f ? -1 : 0);
        return;
    }
    i -= 2359296;
    if (i < 51200) {    // w2 [64][32][5][5] -> w2p [25 tap][2 half][64 oc][16 ic]
        int tap = i >> 11;
        int r = i & 2047;
        int half = r >> 10;
        int r2 = r & 1023;
        int oc = r2 >> 4, j = r2 & 15;
        int ic = half * 16 + j;
        float v = w2[(oc * 32 + ic) * 25 + tap];
        w2p[i] = v > 0.f ? 1 : (v < 0.f ? -1 : 0);
        return;
    }
    i -= 51200;
    if (i < 10240) {    // wf2 sign
        float v = wf2[i];
        wf2p[i] = v > 0.f ? 1 : (v < 0.f ? -1 : 0);
    }
}

// K1: conv1 + bias + BN + sign + pool2 -> act1 channel-last [B][13][13][32] int8
// Block = one image in LDS + 2-float-shifted copy (each window row = 1 b128 read).
__global__ __launch_bounds__(256) void k1_conv1(
        const float* __restrict__ x, const float* __restrict__ k1c,
        signed char* __restrict__ act1) {
    __shared__ __align__(16) float xs[784];
    __shared__ __align__(16) float xs2[784];   // xs2[i] = xs[i+2]
    int b = blockIdx.x, tid = threadIdx.x;
    if (tid < 196) ((float4*)xs)[tid] = ((const float4*)(x + (size_t)b * 784))[tid];
    __syncthreads();
    for (int j = tid; j < 782; j += 256) xs2[j] = xs[j + 2];
    __syncthreads();

    int oc = tid & 31, g = tid >> 5;
    const float* c = k1c + oc * 16;
    float sw[9];
#pragma unroll
    for (int i = 0; i < 9; i++) sw[i] = c[i];
    float bias = c[9], m = c[10], sc = c[11], bb = c[12];
    signed char* dst = act1 + (size_t)b * 5408 + oc;

    for (int i = 0; i < 22; i++) {
        int cell = i * 8 + g;
        if (cell < 169) {
            int py = cell / 13, px = cell - py * 13;
            const float* wnd = (px & 1) ? (xs2 + py * 56 + px * 2 - 2)
                                        : (xs + py * 56 + px * 2);
            float xr[4][4];
#pragma unroll
            for (int dy = 0; dy < 4; dy++) {
                float4 rv = *(const float4*)(wnd + dy * 28);   // aligned b128
                xr[dy][0] = rv.x; xr[dy][1] = rv.y;
                xr[dy][2] = rv.z; xr[dy][3] = rv.w;
            }
            float maxacc = -1e30f;
#pragma unroll
            for (int q = 0; q < 4; q++) {
                int dyp = q >> 1, dxp = q & 1;
                float acc = 0.f;
#pragma unroll
                for (int ky = 0; ky < 3; ky++)
#pragma unroll
                    for (int kx = 0; kx < 3; kx++)
                        acc += xr[dyp + ky][dxp + kx] * sw[ky * 3 + kx];
                maxacc = fmaxf(maxacc, acc);   // BN monotone (sc>0): max commutes
            }
            float bn = (maxacc + bias - m) * sc + bb;  // same assoc as before
            dst[(size_t)cell * 32] = (signed char)fsign(bn);
        }
    }
}

// k1c prep (separate tiny kernel feeding k1)
__global__ void prep_k1(const float* __restrict__ w1, const float* __restrict__ b1,
                        const float* __restrict__ g1, const float* __restrict__ be1,
                        const float* __restrict__ m1, const float* __restrict__ v1,
                        float* __restrict__ k1c) {
    int oc = threadIdx.x;
    if (oc < 32) {
        for (int i = 0; i < 9; i++) k1c[oc * 16 + i] = fsign(w1[oc * 9 + i]);
        k1c[oc * 16 + 9] = b1[oc];
        k1c[oc * 16 + 10] = m1[oc];
        k1c[oc * 16 + 11] = g1[oc] / sqrtf(v1[oc] + 1e-5f);
        k1c[oc * 16 + 12] = be1[oc];
    }
}

// K2: conv2 implicit-GEMM MFMA i8, standalone. Block = 2 images, 9 waves.
// Two half-oc weight passes (25.6 KB each) -> LDS 44.1 KB -> 3 blocks/CU.
// act LDS aswz-swizzled; weight reads lane-contiguous (conflict-free).
#define K2_IMG_STRIDE 9248          // 17*17*32
#define K2_WOFF 18496               // weights one pass: 25*1024 = 25600 B
__device__ __forceinline__ void k2_epilogue(i32x16 A, int oc, int wave, int kh, int b0,
                                            const float* __restrict__ b2,
                                            const float* __restrict__ g2,
                                            const float* __restrict__ be2,
                                            const float* __restrict__ m2,
                                            const float* __restrict__ v2,
                                            signed char* __restrict__ act2) {
    float bias = b2[oc], mm = m2[oc];
    float sc = g2[oc] / sqrtf(v2[oc] + 1e-5f), bb = be2[oc];
#pragma unroll
    for (int g = 0; g < 4; g++) {
        int qo = wave * 8 + kh + 2 * g;      // 0..71 pool cell (2 images)
        int imo = qo / 36, qqo = qo - imo * 36;
        float best = -2.f;
#pragma unroll
        for (int jj = 0; jj < 4; jj++) {     // 4 pool partners live in reg quad
            float z = (float)A[g * 4 + jj] + bias;
            float bn = (z - mm) * sc + bb;
            best = fmaxf(best, fsign(bn));
        }
        act2[((size_t)(b0 + imo) * 64 + oc) * 36 + qqo] = (signed char)best;
    }
}

// stage one half-oc weight pass: linear LDS copy (conflict-free, coalesced)
__device__ __forceinline__ void stage_w(signed char* smem, const signed char* __restrict__ w2p,
                                        int tid, int pass) {
    const i32x4* wsrc = (const i32x4*)w2p;
    i32x4* wdst = (i32x4*)(smem + K2_WOFF);
    for (int i = tid; i < 1600; i += 576) {
        int tap = i >> 6, r = i & 63;
        int half = r >> 5, ocl = r & 31;
        wdst[i] = wsrc[tap * 128 + half * 64 + pass * 32 + ocl];
    }
}

__global__ __launch_bounds__(576) void k2_mfma(
        const signed char* __restrict__ act1, const signed char* __restrict__ w2p,
        const float* __restrict__ b2, const float* __restrict__ g2,
        const float* __restrict__ be2, const float* __restrict__ m2,
        const float* __restrict__ v2, signed char* __restrict__ act2) {
    __shared__ __align__(16) signed char smem[44096];  // act 18496 | w 25600
    int tid = threadIdx.x;
    int b0 = blockIdx.x * 2;

    // zero act region (covers padded borders; swizzle is a bijection on it)
    i32x4* s4 = (i32x4*)smem;
    i32x4 z4 = {0, 0, 0, 0};
    for (int i = tid; i < 1156; i += 576) s4[i] = z4;
    __syncthreads();
    // stage act interior (swizzled) + weights pass A (linear)
    {
        const i32x4* src = (const i32x4*)(act1 + (size_t)b0 * 5408);
        for (int i = tid; i < 676; i += 576) {
            int im = i / 338, r = i - im * 338;
            int pix = r >> 1, half = r & 1;
            int yy = pix / 13 + 2, xx = pix % 13 + 2;
            int off = ((yy * 17 + xx) * 32 + half * 16);
            *(i32x4*)(smem + im * K2_IMG_STRIDE + aswz(off)) = src[i];
        }
    }
    stage_w(smem, w2p, tid, 0);
    __syncthreads();

    // fragment geometry
    int wave = tid >> 6, lane = tid & 63;
    int lrow = lane & 31, kh = lane >> 5;
    int m = wave * 32 + lrow;
    int q = m >> 2, j = m & 3;
    int img = q / 36, qq = q - img * 36;
    int oy = 2 * (qq / 6) + (j >> 1);
    int ox = 2 * (qq - (qq / 6) * 6) + (j & 1);
    const signed char* aimg = smem + img * K2_IMG_STRIDE;
    int pixbase = oy * 17 + ox;
    const signed char* wbase = smem + K2_WOFF + kh * 512 + lrow * 16;

    // pass A: oc = lrow
    i32x16 acc0 = {0};
#pragma unroll 5
    for (int tap = 0; tap < 25; ++tap) {
        int ky = tap / 5, kx = tap - (tap / 5) * 5;
        int off = (pixbase + ky * 17 + kx) * 32 + kh * 16;
        i32x4 a = *(const i32x4*)(aimg + aswz(off));
        i32x4 w0 = *(const i32x4*)(wbase + tap * 1024);
        acc0 = __builtin_amdgcn_mfma_i32_32x32x32_i8(a, w0, acc0, 0, 0, 0);
    }
    __syncthreads();                       // all reads of pass-A weights done
    stage_w(smem, w2p, tid, 1);            // overwrite with pass-B weights
    k2_epilogue(acc0, lrow, wave, kh, b0, b2, g2, be2, m2, v2, act2);
    __syncthreads();

    // pass B: oc = 32 + lrow
    i32x16 acc1 = {0};
#pragma unroll 5
    for (int tap = 0; tap < 25; ++tap) {
        int ky = tap / 5, kx = tap - (tap / 5) * 5;
        int off = (pixbase + ky * 17 + kx) * 32 + kh * 16;
        i32x4 a = *(const i32x4*)(aimg + aswz(off));
        i32x4 w1v = *(const i32x4*)(wbase + tap * 1024);
        acc1 = __builtin_amdgcn_mfma_i32_32x32x32_i8(a, w1v, acc1, 0, 0, 0);
    }
    k2_epilogue(acc1, 32 + lrow, wave, kh, b0, b2, g2, be2, m2, v2, act2);
}

// K3: fc1 as LDS-tiled MFMA i8 GEMM 2048x1024x2304. (r11 verbatim)
#define K3A_SEG 2064                // 128*16 + 16 pad
#define K3B_SEG 1040                // 64*16 + 16 pad
#define K3_BOFF 16512               // 8 * 2064
__global__ __launch_bounds__(256) void k3_mfma(
        const signed char* __restrict__ act2, const signed char* __restrict__ wf1s,
        const float* __restrict__ bf1, const float* __restrict__ gf1,
        const float* __restrict__ bef1, const float* __restrict__ mf1,
        const float* __restrict__ vf1, signed char* __restrict__ act3) {
    __shared__ __align__(16) signed char s[K3_BOFF + 8 * K3B_SEG];  // 24832
    int tid = threadIdx.x;
    int bid = blockIdx.x;
    int tn = bid & 15, tm = bid >> 4;

    const signed char* Ab = act2 + (size_t)tm * 128 * 2304;
    const signed char* Bb = wf1s + (size_t)tn * 64 * 2304;
    size_t gA[4]; int lwA[4];
#pragma unroll
    for (int i = 0; i < 4; i++) {
        int e = tid + 256 * i, row = e >> 3, sg = (e + row) & 7;
        gA[i] = (size_t)row * 2304 + sg * 16;
        lwA[i] = sg * K3A_SEG + row * 16;
    }
    size_t gB[2]; int lwB[2];
#pragma unroll
    for (int i = 0; i < 2; i++) {
        int e = tid + 256 * i, row = e >> 3, sg = (e + row) & 7;
        gB[i] = (size_t)row * 2304 + sg * 16;
        lwB[i] = K3_BOFF + sg * K3B_SEG + row * 16;
    }

    i32x4 ra[4], rb[2];
#pragma unroll
    for (int i = 0; i < 4; i++) ra[i] = *(const i32x4*)(Ab + gA[i]);
#pragma unroll
    for (int i = 0; i < 2; i++) rb[i] = *(const i32x4*)(Bb + gB[i]);

    int l = tid & 63, wid = tid >> 6;
    int lrow = l & 31, kh = l >> 5;
    int raddrA = kh * K3A_SEG + (wid * 32 + lrow) * 16;
    int raddrB0 = K3_BOFF + kh * K3B_SEG + lrow * 16;
    int raddrB1 = raddrB0 + 32 * 16;

    i32x16 acc0 = {0};
    i32x16 acc1 = {0};
    for (int t = 0; t < 18; ++t) {
        if (t) __syncthreads();
#pragma unroll
        for (int i = 0; i < 4; i++) *(i32x4*)(s + lwA[i]) = ra[i];
#pragma unroll
        for (int i = 0; i < 2; i++) *(i32x4*)(s + lwB[i]) = rb[i];
        if (t < 17) {
            size_t ko = (size_t)(t + 1) * 128;
#pragma unroll
            for (int i = 0; i < 4; i++) ra[i] = *(const i32x4*)(Ab + gA[i] + ko);
#pragma unroll
            for (int i = 0; i < 2; i++) rb[i] = *(const i32x4*)(Bb + gB[i] + ko);
        }
        __syncthreads();
#pragma unroll
        for (int ks = 0; ks < 4; ++ks) {
            i32x4 a  = *(const i32x4*)(s + raddrA + ks * 2 * K3A_SEG);
            i32x4 b0 = *(const i32x4*)(s + raddrB0 + ks * 2 * K3B_SEG);
            i32x4 b1 = *(const i32x4*)(s + raddrB1 + ks * 2 * K3B_SEG);
            acc0 = __builtin_amdgcn_mfma_i32_32x32x32_i8(a, b0, acc0, 0, 0, 0);
            acc1 = __builtin_amdgcn_mfma_i32_32x32x32_i8(a, b1, acc1, 0, 0, 0);
        }
    }

    int col0 = tn * 64 + lrow;
    int col1 = col0 + 32;
    float bi0 = bf1[col0], m0 = mf1[col0];
    float sc0 = gf1[col0] / sqrtf(vf1[col0] + 1e-5f), bb0 = bef1[col0];
    float bi1 = bf1[col1], m1 = mf1[col1];
    float sc1 = gf1[col1] / sqrtf(vf1[col1] + 1e-5f), bb1 = bef1[col1];
#pragma unroll
    for (int r = 0; r < 16; r++) {
        int row = tm * 128 + wid * 32 + (r & 3) + 8 * (r >> 2) + 4 * kh;
        float bn0 = ((float)acc0[r] + bi0 - m0) * sc0 + bb0;
        float bn1 = ((float)acc1[r] + bi1 - m1) * sc1 + bb1;
        act3[(size_t)row * 1024 + col0] = (signed char)fsign(bn0);
        act3[(size_t)row * 1024 + col1] = (signed char)fsign(bn1);
    }
}

// K4: fc2 (1024->10) + bias + BN + log_softmax. One wave per image. (r11 verbatim)
__global__ void k4_fc2(const signed char* __restrict__ act3, const signed char* __restrict__ swf2,
                       const float* __restrict__ bf2, const float* __restrict__ gf2,
                       const float* __restrict__ bef2, const float* __restrict__ mf2,
                       const float* __restrict__ vf2, float* __restrict__ out) {
    int wid = (blockIdx.x * 256 + threadIdx.x) >> 6;
    int lane = threadIdx.x & 63;
    if (wid >= BATCH) return;
    const int* hd = (const int*)act3 + (size_t)wid * 256;
    const int* wd = (const int*)swf2;
    int acc[10];
#pragma unroll
    for (int o = 0; o < 10; o++) acc[o] = 0;
#pragma unroll
    for (int i = 0; i < 4; i++) {
        int k4 = i * 64 + lane;
        int hv = hd[k4];
#pragma unroll
        for (int o = 0; o < 10; o++)
            acc[o] = sdot4(hv, wd[o * 256 + k4], acc[o]);
    }
#pragma unroll
    for (int o = 0; o < 10; o++)
#pragma unroll
        for (int s = 32; s > 0; s >>= 1) acc[o] += __shfl_xor(acc[o], s);
    if (lane == 0) {
        float logit[10];
        float mx = -1e30f;
#pragma unroll
        for (int o = 0; o < 10; o++) {
            float z = (float)acc[o] + bf2[o];
            float bn = (z - mf2[o]) * (gf2[o] / sqrtf(vf2[o] + 1e-5f)) + bef2[o];
            logit[o] = bn;
            mx = fmaxf(mx, bn);
        }
        float s = 0.f;
#pragma unroll
        for (int o = 0; o < 10; o++) s += expf(logit[o] - mx);
        float lse = mx + logf(s);
#pragma unroll
        for (int o = 0; o < 10; o++) out[(size_t)wid * 10 + o] = logit[o] - lse;
    }
}

extern "C" void kernel_launch(void* const* d_in, const int* in_sizes, int n_in,
                              void* d_out, int out_size, void* d_ws, size_t ws_size,
                              hipStream_t stream) {
    const float* x   = (const float*)d_in[0];
    const float* w1  = (const float*)d_in[1];
    const float* b1  = (const float*)d_in[2];
    const float* g1  = (const float*)d_in[3];
    const float* be1 = (const float*)d_in[4];
    const float* m1  = (const float*)d_in[5];
    const float* v1  = (const float*)d_in[6];
    const float* w2  = (const float*)d_in[7];
    const float* b2  = (const float*)d_in[8];
    const float* g2  = (const float*)d_in[9];
    const float* be2 = (const float*)d_in[10];
    const float* m2  = (const float*)d_in[11];
    const float* v2  = (const float*)d_in[12];
    const float* wf1 = (const float*)d_in[13];
    const float* bf1 = (const float*)d_in[14];
    const float* gf1 = (const float*)d_in[15];
    const float* bef1= (const float*)d_in[16];
    const float* mf1 = (const float*)d_in[17];
    const float* vf1 = (const float*)d_in[18];
    const float* wf2 = (const float*)d_in[19];
    const float* bf2 = (const float*)d_in[20];
    const float* gf2 = (const float*)d_in[21];
    const float* bef2= (const float*)d_in[22];
    const float* mf2 = (const float*)d_in[23];
    const float* vf2 = (const float*)d_in[24];
    float* out = (float*)d_out;

    // ws layout (all int8 unless noted)
    char* ws = (char*)d_ws;
    signed char* act1 = (signed char*)ws;                  // 2048*169*32   = 11,075,584
    signed char* act2 = act1 + 11075584;                   // 2048*2304     =  4,718,592
    signed char* act3 = act2 + 4718592;                    // 2048*1024     =  2,097,152
    signed char* w2p  = act3 + 2097152;                    // 25*2*64*16    =     51,200
    signed char* wf1s = w2p + 51200;                       // 1024*2304     =  2,359,296
    signed char* wf2p = wf1s + 2359296;                    // 10*1024       =     10,240
    float* k1c = (float*)(wf2p + 10240);                   // 32*16 floats  =      2,048 B

    prep_k1<<<1, 64, 0, stream>>>(w1, b1, g1, be1, m1, v1, k1c);
    prep_all<<<9456, 256, 0, stream>>>(w2, wf1, wf2, w2p, wf1s, wf2p);

    k1_conv1<<<2048, 256, 0, stream>>>(x, k1c, act1);

    k2_mfma<<<1024, 576, 0, stream>>>(act1, w2p, b2, g2, be2, m2, v2, act2);

    k3_mfma<<<256, 256, 0, stream>>>(act2, wf1s, bf1, gf1, bef1, mf1, vf1, act3);

    k4_fc2<<<512, 256, 0, stream>>>(act3, wf2p, bf2, gf2, bef2, mf2, vf2, out);
}

// Round 18
// 82.630 us; speedup vs baseline: 1.1853x; 1.0899x over previous
//
#include <hip/hip_runtime.h>
#include <math.h>

#define BATCH 2048

typedef __attribute__((ext_vector_type(4))) int i32x4;
typedef __attribute__((ext_vector_type(16))) int i32x16;

__device__ __forceinline__ int sdot4(int a, int b, int c) {
    return __builtin_amdgcn_sdot4(a, b, c, false);
}

__device__ __forceinline__ float fsign(float v) {
    return v > 0.f ? 1.f : (v < 0.f ? -1.f : 0.f);
}

// act swizzle (T2): flips addr bits 4-6 by pixel bits 2-4; bijective on [0,9248),
// keeps 16B chunks intact, independent of the low 5 bits (oc).
__device__ __forceinline__ int aswz(int off) {
    return off ^ (((off >> 7) & 7) << 4);
}

// Fused prep: wf1 binarize | w2 pack [tap][half][oc][16] | wf2 binarize | k1c table
__global__ void prep_all(const float* __restrict__ w1, const float* __restrict__ b1,
                         const float* __restrict__ g1, const float* __restrict__ be1,
                         const float* __restrict__ m1, const float* __restrict__ v1,
                         const float* __restrict__ w2, const float* __restrict__ wf1,
                         const float* __restrict__ wf2,
                         signed char* __restrict__ w2p, signed char* __restrict__ wf1s,
                         signed char* __restrict__ wf2p, float* __restrict__ k1c) {
    int i = blockIdx.x * 256 + threadIdx.x;
    if (i < 2359296) {  // wf1 sign (natural [1024][2304] layout)
        float v = wf1[i];
        wf1s[i] = v > 0.f ? 1 : (v < 0.f ? -1 : 0);
        return;
    }
    i -= 2359296;
    if (i < 51200) {    // w2 [64][32][5][5] -> w2p [25 tap][2 khalf][64 oc][16 ic]
        int tap = i >> 11;
        int r = i & 2047;
        int half = r >> 10;
        int r2 = r & 1023;
        int oc = r2 >> 4, j = r2 & 15;
        int ic = half * 16 + j;
        float v = w2[(oc * 32 + ic) * 25 + tap];
        w2p[i] = v > 0.f ? 1 : (v < 0.f ? -1 : 0);
        return;
    }
    i -= 51200;
    if (i < 10240) {    // wf2 sign
        float v = wf2[i];
        wf2p[i] = v > 0.f ? 1 : (v < 0.f ? -1 : 0);
        return;
    }
    i -= 10240;
    if (i < 416) {      // k1c [32][16] = {sw0..8, bias, m, sc, bb}
        int oc = i / 13, s = i - oc * 13;
        float r;
        if (s < 9) r = fsign(w1[oc * 9 + s]);
        else if (s == 9) r = b1[oc];
        else if (s == 10) r = m1[oc];
        else if (s == 11) r = g1[oc] / sqrtf(v1[oc] + 1e-5f);
        else r = be1[oc];
        k1c[oc * 16 + s] = r;
    }
}

// K1: conv1 + bias + BN + sign + pool2 -> act1 in k2's padded+swizzled layout:
// per image 9248 B = 17x17 zero-bordered pixels x 32 oc, byte at aswz(pix*32+oc).
// Block = one image in LDS + 2-float-shifted copy (window row = one b128 read).
__global__ __launch_bounds__(256) void k1_conv1(
        const float* __restrict__ x, const float* __restrict__ k1c,
        signed char* __restrict__ act1) {
    __shared__ __align__(16) float xs[784];
    __shared__ __align__(16) float xs2[784];   // xs2[i] = xs[i+2]
    int b = blockIdx.x, tid = threadIdx.x;
    if (tid < 196) ((float4*)xs)[tid] = ((const float4*)(x + (size_t)b * 784))[tid];
    __syncthreads();
    for (int j = tid; j < 782; j += 256) xs2[j] = xs[j + 2];

    signed char* img = act1 + (size_t)b * 9248;
    // zero the 120 border pixels (240 x 16B chunks)
    i32x4 z4 = {0, 0, 0, 0};
    for (int i = tid; i < 240; i += 256) {
        int pi = i >> 1, half = i & 1;
        int p;
        if (pi < 34) p = pi;                       // rows 0-1
        else if (pi < 68) p = 255 + (pi - 34);     // rows 15-16
        else {                                     // rows 2-14, cols 0,1,15,16
            int j2 = pi - 68;
            int row = 2 + (j2 >> 2), c = j2 & 3;
            int col = (c < 2) ? c : 13 + c;        // 0,1,15,16
            p = row * 17 + col;
        }
        *(i32x4*)(img + aswz(p * 32 + half * 16)) = z4;
    }
    __syncthreads();

    int oc = tid & 31, g = tid >> 5;
    const float* c = k1c + oc * 16;
    float sw[9];
#pragma unroll
    for (int i = 0; i < 9; i++) sw[i] = c[i];
    float bias = c[9], m = c[10], sc = c[11], bb = c[12];

    for (int i = 0; i < 22; i++) {
        int cell = i * 8 + g;
        if (cell < 169) {
            int py = cell / 13, px = cell - py * 13;
            const float* wnd = (px & 1) ? (xs2 + py * 56 + px * 2 - 2)
                                        : (xs + py * 56 + px * 2);
            float xr[4][4];
#pragma unroll
            for (int dy = 0; dy < 4; dy++) {
                float4 rv = *(const float4*)(wnd + dy * 28);   // aligned b128
                xr[dy][0] = rv.x; xr[dy][1] = rv.y;
                xr[dy][2] = rv.z; xr[dy][3] = rv.w;
            }
            float maxacc = -1e30f;
#pragma unroll
            for (int q = 0; q < 4; q++) {
                int dyp = q >> 1, dxp = q & 1;
                float acc = 0.f;
#pragma unroll
                for (int ky = 0; ky < 3; ky++)
#pragma unroll
                    for (int kx = 0; kx < 3; kx++)
                        acc += xr[dyp + ky][dxp + kx] * sw[ky * 3 + kx];
                maxacc = fmaxf(maxacc, acc);   // BN monotone (sc>0): max commutes
            }
            float bn = (maxacc + bias - m) * sc + bb;  // same assoc as before
            int p32 = ((py + 2) * 17 + (px + 2)) * 32;
            img[aswz(p32 + oc)] = (signed char)fsign(bn);
        }
    }
}

// K2: conv2 implicit-GEMM MFMA i8, one-pass. Block = 2 images, 9 waves.
// Staging is PURE LINEAR COPY (act pre-swizzled in global by k1; weights
// pre-packed [tap][half][oc]). LDS 69,696 B -> 2 blocks/CU.
#define K2_IMG_STRIDE 9248          // 17*17*32
#define K2_WOFF 18496               // weights: 25*2048 = 51,200 B
__device__ __forceinline__ void k2_epilogue(i32x16 A, int oc, int wave, int kh, int b0,
                                            const float* __restrict__ b2,
                                            const float* __restrict__ g2,
                                            const float* __restrict__ be2,
                                            const float* __restrict__ m2,
                                            const float* __restrict__ v2,
                                            signed char* __restrict__ act2) {
    float bias = b2[oc], mm = m2[oc];
    float sc = g2[oc] / sqrtf(v2[oc] + 1e-5f), bb = be2[oc];
#pragma unroll
    for (int g = 0; g < 4; g++) {
        int qo = wave * 8 + kh + 2 * g;      // 0..71 pool cell (2 images)
        int imo = qo / 36, qqo = qo - imo * 36;
        float best = -2.f;
#pragma unroll
        for (int jj = 0; jj < 4; jj++) {     // 4 pool partners live in reg quad
            float z = (float)A[g * 4 + jj] + bias;
            float bn = (z - mm) * sc + bb;
            best = fmaxf(best, fsign(bn));
        }
        act2[((size_t)(b0 + imo) * 64 + oc) * 36 + qqo] = (signed char)best;
    }
}

__global__ __launch_bounds__(576) void k2_mfma(
        const signed char* __restrict__ act1, const signed char* __restrict__ w2p,
        const float* __restrict__ b2, const float* __restrict__ g2,
        const float* __restrict__ be2, const float* __restrict__ m2,
        const float* __restrict__ v2, signed char* __restrict__ act2) {
    __shared__ __align__(16) signed char smem[69696];  // act 18496 | w 51200
    int tid = threadIdx.x;
    int b0 = blockIdx.x * 2;

    // linear staging: fully coalesced global reads, conflict-free LDS writes
    {
        const i32x4* asrc = (const i32x4*)(act1 + (size_t)b0 * 9248);
        i32x4* s4 = (i32x4*)smem;
        for (int i = tid; i < 1156; i += 576) s4[i] = asrc[i];
        const i32x4* wsrc = (const i32x4*)w2p;
        i32x4* w4 = (i32x4*)(smem + K2_WOFF);
        for (int i = tid; i < 3200; i += 576) w4[i] = wsrc[i];
    }
    __syncthreads();

    // fragment geometry
    int wave = tid >> 6, lane = tid & 63;
    int lrow = lane & 31, kh = lane >> 5;
    int m = wave * 32 + lrow;
    int q = m >> 2, j = m & 3;
    int img = q / 36, qq = q - img * 36;
    int oy = 2 * (qq / 6) + (j >> 1);
    int ox = 2 * (qq - (qq / 6) * 6) + (j & 1);
    const signed char* aimg = smem + img * K2_IMG_STRIDE;
    int pixbase = oy * 17 + ox;
    const signed char* wbase = smem + K2_WOFF + kh * 1024 + lrow * 16;

    i32x16 acc0 = {0};
    i32x16 acc1 = {0};
#pragma unroll 5
    for (int tap = 0; tap < 25; ++tap) {
        int ky = tap / 5, kx = tap - (tap / 5) * 5;
        int off = (pixbase + ky * 17 + kx) * 32 + kh * 16;
        i32x4 a = *(const i32x4*)(aimg + aswz(off));
        i32x4 w0 = *(const i32x4*)(wbase + tap * 2048);        // oc = lrow
        i32x4 w1v = *(const i32x4*)(wbase + tap * 2048 + 512); // oc = 32+lrow
        acc0 = __builtin_amdgcn_mfma_i32_32x32x32_i8(a, w0, acc0, 0, 0, 0);
        acc1 = __builtin_amdgcn_mfma_i32_32x32x32_i8(a, w1v, acc1, 0, 0, 0);
    }
    k2_epilogue(acc0, lrow,      wave, kh, b0, b2, g2, be2, m2, v2, act2);
    k2_epilogue(acc1, 32 + lrow, wave, kh, b0, b2, g2, be2, m2, v2, act2);
}

// K3: fc1 as LDS-tiled MFMA i8 GEMM 2048x1024x2304. (r11 verbatim)
#define K3A_SEG 2064                // 128*16 + 16 pad
#define K3B_SEG 1040                // 64*16 + 16 pad
#define K3_BOFF 16512               // 8 * 2064
__global__ __launch_bounds__(256) void k3_mfma(
        const signed char* __restrict__ act2, const signed char* __restrict__ wf1s,
        const float* __restrict__ bf1, const float* __restrict__ gf1,
        const float* __restrict__ bef1, const float* __restrict__ mf1,
        const float* __restrict__ vf1, signed char* __restrict__ act3) {
    __shared__ __align__(16) signed char s[K3_BOFF + 8 * K3B_SEG];  // 24832
    int tid = threadIdx.x;
    int bid = blockIdx.x;
    int tn = bid & 15, tm = bid >> 4;

    const signed char* Ab = act2 + (size_t)tm * 128 * 2304;
    const signed char* Bb = wf1s + (size_t)tn * 64 * 2304;
    size_t gA[4]; int lwA[4];
#pragma unroll
    for (int i = 0; i < 4; i++) {
        int e = tid + 256 * i, row = e >> 3, sg = (e + row) & 7;
        gA[i] = (size_t)row * 2304 + sg * 16;
        lwA[i] = sg * K3A_SEG + row * 16;
    }
    size_t gB[2]; int lwB[2];
#pragma unroll
    for (int i = 0; i < 2; i++) {
        int e = tid + 256 * i, row = e >> 3, sg = (e + row) & 7;
        gB[i] = (size_t)row * 2304 + sg * 16;
        lwB[i] = K3_BOFF + sg * K3B_SEG + row * 16;
    }

    i32x4 ra[4], rb[2];
#pragma unroll
    for (int i = 0; i < 4; i++) ra[i] = *(const i32x4*)(Ab + gA[i]);
#pragma unroll
    for (int i = 0; i < 2; i++) rb[i] = *(const i32x4*)(Bb + gB[i]);

    int l = tid & 63, wid = tid >> 6;
    int lrow = l & 31, kh = l >> 5;
    int raddrA = kh * K3A_SEG + (wid * 32 + lrow) * 16;
    int raddrB0 = K3_BOFF + kh * K3B_SEG + lrow * 16;
    int raddrB1 = raddrB0 + 32 * 16;

    i32x16 acc0 = {0};
    i32x16 acc1 = {0};
    for (int t = 0; t < 18; ++t) {
        if (t) __syncthreads();
#pragma unroll
        for (int i = 0; i < 4; i++) *(i32x4*)(s + lwA[i]) = ra[i];
#pragma unroll
        for (int i = 0; i < 2; i++) *(i32x4*)(s + lwB[i]) = rb[i];
        if (t < 17) {
            size_t ko = (size_t)(t + 1) * 128;
#pragma unroll
            for (int i = 0; i < 4; i++) ra[i] = *(const i32x4*)(Ab + gA[i] + ko);
#pragma unroll
            for (int i = 0; i < 2; i++) rb[i] = *(const i32x4*)(Bb + gB[i] + ko);
        }
        __syncthreads();
#pragma unroll
        for (int ks = 0; ks < 4; ++ks) {
            i32x4 a  = *(const i32x4*)(s + raddrA + ks * 2 * K3A_SEG);
            i32x4 b0 = *(const i32x4*)(s + raddrB0 + ks * 2 * K3B_SEG);
            i32x4 b1 = *(const i32x4*)(s + raddrB1 + ks * 2 * K3B_SEG);
            acc0 = __builtin_amdgcn_mfma_i32_32x32x32_i8(a, b0, acc0, 0, 0, 0);
            acc1 = __builtin_amdgcn_mfma_i32_32x32x32_i8(a, b1, acc1, 0, 0, 0);
        }
    }

    int col0 = tn * 64 + lrow;
    int col1 = col0 + 32;
    float bi0 = bf1[col0], m0 = mf1[col0];
    float sc0 = gf1[col0] / sqrtf(vf1[col0] + 1e-5f), bb0 = bef1[col0];
    float bi1 = bf1[col1], m1 = mf1[col1];
    float sc1 = gf1[col1] / sqrtf(vf1[col1] + 1e-5f), bb1 = bef1[col1];
#pragma unroll
    for (int r = 0; r < 16; r++) {
        int row = tm * 128 + wid * 32 + (r & 3) + 8 * (r >> 2) + 4 * kh;
        float bn0 = ((float)acc0[r] + bi0 - m0) * sc0 + bb0;
        float bn1 = ((float)acc1[r] + bi1 - m1) * sc1 + bb1;
        act3[(size_t)row * 1024 + col0] = (signed char)fsign(bn0);
        act3[(size_t)row * 1024 + col1] = (signed char)fsign(bn1);
    }
}

// K4: fc2 (1024->10) + bias + BN + log_softmax. One wave per image. (r11 verbatim)
__global__ void k4_fc2(const signed char* __restrict__ act3, const signed char* __restrict__ swf2,
                       const float* __restrict__ bf2, const float* __restrict__ gf2,
                       const float* __restrict__ bef2, const float* __restrict__ mf2,
                       const float* __restrict__ vf2, float* __restrict__ out) {
    int wid = (blockIdx.x * 256 + threadIdx.x) >> 6;
    int lane = threadIdx.x & 63;
    if (wid >= BATCH) return;
    const int* hd = (const int*)act3 + (size_t)wid * 256;
    const int* wd = (const int*)swf2;
    int acc[10];
#pragma unroll
    for (int o = 0; o < 10; o++) acc[o] = 0;
#pragma unroll
    for (int i = 0; i < 4; i++) {
        int k4 = i * 64 + lane;
        int hv = hd[k4];
#pragma unroll
        for (int o = 0; o < 10; o++)
            acc[o] = sdot4(hv, wd[o * 256 + k4], acc[o]);
    }
#pragma unroll
    for (int o = 0; o < 10; o++)
#pragma unroll
        for (int s = 32; s > 0; s >>= 1) acc[o] += __shfl_xor(acc[o], s);
    if (lane == 0) {
        float logit[10];
        float mx = -1e30f;
#pragma unroll
        for (int o = 0; o < 10; o++) {
            float z = (float)acc[o] + bf2[o];
            float bn = (z - mf2[o]) * (gf2[o] / sqrtf(vf2[o] + 1e-5f)) + bef2[o];
            logit[o] = bn;
            mx = fmaxf(mx, bn);
        }
        float s = 0.f;
#pragma unroll
        for (int o = 0; o < 10; o++) s += expf(logit[o] - mx);
        float lse = mx + logf(s);
#pragma unroll
        for (int o = 0; o < 10; o++) out[(size_t)wid * 10 + o] = logit[o] - lse;
    }
}

extern "C" void kernel_launch(void* const* d_in, const int* in_sizes, int n_in,
                              void* d_out, int out_size, void* d_ws, size_t ws_size,
                              hipStream_t stream) {
    const float* x   = (const float*)d_in[0];
    const float* w1  = (const float*)d_in[1];
    const float* b1  = (const float*)d_in[2];
    const float* g1  = (const float*)d_in[3];
    const float* be1 = (const float*)d_in[4];
    const float* m1  = (const float*)d_in[5];
    const float* v1  = (const float*)d_in[6];
    const float* w2  = (const float*)d_in[7];
    const float* b2  = (const float*)d_in[8];
    const float* g2  = (const float*)d_in[9];
    const float* be2 = (const float*)d_in[10];
    const float* m2  = (const float*)d_in[11];
    const float* v2  = (const float*)d_in[12];
    const float* wf1 = (const float*)d_in[13];
    const float* bf1 = (const float*)d_in[14];
    const float* gf1 = (const float*)d_in[15];
    const float* bef1= (const float*)d_in[16];
    const float* mf1 = (const float*)d_in[17];
    const float* vf1 = (const float*)d_in[18];
    const float* wf2 = (const float*)d_in[19];
    const float* bf2 = (const float*)d_in[20];
    const float* gf2 = (const float*)d_in[21];
    const float* bef2= (const float*)d_in[22];
    const float* mf2 = (const float*)d_in[23];
    const float* vf2 = (const float*)d_in[24];
    float* out = (float*)d_out;

    // ws layout (all int8 unless noted)
    char* ws = (char*)d_ws;
    signed char* act1 = (signed char*)ws;                  // 2048*9248     = 18,939,904
    signed char* act2 = act1 + 18939904;                   // 2048*2304     =  4,718,592
    signed char* act3 = act2 + 4718592;                    // 2048*1024     =  2,097,152
    signed char* w2p  = act3 + 2097152;                    // 25*2*64*16    =     51,200
    signed char* wf1s = w2p + 51200;                       // 1024*2304     =  2,359,296
    signed char* wf2p = wf1s + 2359296;                    // 10*1024       =     10,240
    float* k1c = (float*)(wf2p + 10240);                   // 32*16 floats  =      2,048 B

    // prep: 2,359,296 + 51,200 + 10,240 + 416 = 2,421,152 elems -> 9458 blocks
    prep_all<<<9458, 256, 0, stream>>>(w1, b1, g1, be1, m1, v1, w2, wf1, wf2,
                                       w2p, wf1s, wf2p, k1c);

    k1_conv1<<<2048, 256, 0, stream>>>(x, k1c, act1);

    k2_mfma<<<1024, 576, 0, stream>>>(act1, w2p, b2, g2, be2, m2, v2, act2);

    k3_mfma<<<256, 256, 0, stream>>>(act2, wf1s, bf1, gf1, bef1, mf1, vf1, act3);

    k4_fc2<<<512, 256, 0, stream>>>(act3, wf2p, bf2, gf2, bef2, mf2, vf2, out);
}

// Round 19
// 76.310 us; speedup vs baseline: 1.2834x; 1.0828x over previous
//
#include <hip/hip_runtime.h>
#include <math.h>

#define BATCH 2048

typedef __attribute__((ext_vector_type(4))) int i32x4;
typedef __attribute__((ext_vector_type(16))) int i32x16;

__device__ __forceinline__ int sdot4(int a, int b, int c) {
    return __builtin_amdgcn_sdot4(a, b, c, false);
}

__device__ __forceinline__ float fsign(float v) {
    return v > 0.f ? 1.f : (v < 0.f ? -1.f : 0.f);
}

// act swizzle (T2): flips addr bits 4-6 by pixel bits 2-4; bijective on [0,9248),
// keeps 16B chunks intact, independent of the low 5 bits (oc).
__device__ __forceinline__ int aswz(int off) {
    return off ^ (((off >> 7) & 7) << 4);
}

// Fused prep: wf1 binarize | w2 pack [tap][half][oc][16] | wf2 binarize | k1c table
__global__ void prep_all(const float* __restrict__ w1, const float* __restrict__ b1,
                         const float* __restrict__ g1, const float* __restrict__ be1,
                         const float* __restrict__ m1, const float* __restrict__ v1,
                         const float* __restrict__ w2, const float* __restrict__ wf1,
                         const float* __restrict__ wf2,
                         signed char* __restrict__ w2p, signed char* __restrict__ wf1s,
                         signed char* __restrict__ wf2p, float* __restrict__ k1c) {
    int i = blockIdx.x * 256 + threadIdx.x;
    if (i < 2359296) {  // wf1 sign (natural [1024][2304] layout)
        float v = wf1[i];
        wf1s[i] = v > 0.f ? 1 : (v < 0.f ? -1 : 0);
        return;
    }
    i -= 2359296;
    if (i < 51200) {    // w2 [64][32][5][5] -> w2p [25 tap][2 khalf][64 oc][16 ic]
        int tap = i >> 11;
        int r = i & 2047;
        int half = r >> 10;
        int r2 = r & 1023;
        int oc = r2 >> 4, j = r2 & 15;
        int ic = half * 16 + j;
        float v = w2[(oc * 32 + ic) * 25 + tap];
        w2p[i] = v > 0.f ? 1 : (v < 0.f ? -1 : 0);
        return;
    }
    i -= 51200;
    if (i < 10240) {    // wf2 sign
        float v = wf2[i];
        wf2p[i] = v > 0.f ? 1 : (v < 0.f ? -1 : 0);
        return;
    }
    i -= 10240;
    if (i < 416) {      // k1c [32][16] = {sw0..8, bias, m, sc, bb}
        int oc = i / 13, s = i - oc * 13;
        float r;
        if (s < 9) r = fsign(w1[oc * 9 + s]);
        else if (s == 9) r = b1[oc];
        else if (s == 10) r = m1[oc];
        else if (s == 11) r = g1[oc] / sqrtf(v1[oc] + 1e-5f);
        else r = be1[oc];
        k1c[oc * 16 + s] = r;
    }
}

// K1: conv1 + bias + BN + sign + pool2 -> act1 in k2's padded+swizzled layout:
// per image 9248 B = 17x17 zero-bordered pixels x 32 oc, byte at aswz(pix*32+oc).
__global__ __launch_bounds__(256) void k1_conv1(
        const float* __restrict__ x, const float* __restrict__ k1c,
        signed char* __restrict__ act1) {
    __shared__ __align__(16) float xs[784];
    __shared__ __align__(16) float xs2[784];   // xs2[i] = xs[i+2]
    int b = blockIdx.x, tid = threadIdx.x;
    if (tid < 196) ((float4*)xs)[tid] = ((const float4*)(x + (size_t)b * 784))[tid];
    __syncthreads();
    for (int j = tid; j < 782; j += 256) xs2[j] = xs[j + 2];

    signed char* img = act1 + (size_t)b * 9248;
    // zero the 120 border pixels (240 x 16B chunks)
    i32x4 z4 = {0, 0, 0, 0};
    for (int i = tid; i < 240; i += 256) {
        int pi = i >> 1, half = i & 1;
        int p;
        if (pi < 34) p = pi;                       // rows 0-1
        else if (pi < 68) p = 255 + (pi - 34);     // rows 15-16
        else {                                     // rows 2-14, cols 0,1,15,16
            int j2 = pi - 68;
            int row = 2 + (j2 >> 2), c = j2 & 3;
            int col = (c < 2) ? c : 13 + c;        // 0,1,15,16
            p = row * 17 + col;
        }
        *(i32x4*)(img + aswz(p * 32 + half * 16)) = z4;
    }
    __syncthreads();

    int oc = tid & 31, g = tid >> 5;
    const float* c = k1c + oc * 16;
    float sw[9];
#pragma unroll
    for (int i = 0; i < 9; i++) sw[i] = c[i];
    float bias = c[9], m = c[10], sc = c[11], bb = c[12];

    for (int i = 0; i < 22; i++) {
        int cell = i * 8 + g;
        if (cell < 169) {
            int py = cell / 13, px = cell - py * 13;
            const float* wnd = (px & 1) ? (xs2 + py * 56 + px * 2 - 2)
                                        : (xs + py * 56 + px * 2);
            float xr[4][4];
#pragma unroll
            for (int dy = 0; dy < 4; dy++) {
                float4 rv = *(const float4*)(wnd + dy * 28);   // aligned b128
                xr[dy][0] = rv.x; xr[dy][1] = rv.y;
                xr[dy][2] = rv.z; xr[dy][3] = rv.w;
            }
            float maxacc = -1e30f;
#pragma unroll
            for (int q = 0; q < 4; q++) {
                int dyp = q >> 1, dxp = q & 1;
                float acc = 0.f;
#pragma unroll
                for (int ky = 0; ky < 3; ky++)
#pragma unroll
                    for (int kx = 0; kx < 3; kx++)
                        acc += xr[dyp + ky][dxp + kx] * sw[ky * 3 + kx];
                maxacc = fmaxf(maxacc, acc);   // BN monotone (sc>0): max commutes
            }
            float bn = (maxacc + bias - m) * sc + bb;  // same assoc as before
            int p32 = ((py + 2) * 17 + (px + 2)) * 32;
            img[aswz(p32 + oc)] = (signed char)fsign(bn);
        }
    }
}

// K2: conv2 implicit-GEMM MFMA i8. Block = 8 images, 12 waves (768 thr).
// Grid = 256 = exactly 1 block/CU, zero tail. Each wave: 3 M-tiles x both
// oc-halves, tap-major (weight fragments reused across 3 tiles).
// LDS 125,184 B = act 73,984 | w 51,200. Staging = pure linear copy.
#define K2_IMG_STRIDE 9248          // 17*17*32
#define K2_WOFF 73984               // 8*9248
__global__ __launch_bounds__(768) void k2_mfma(
        const signed char* __restrict__ act1, const signed char* __restrict__ w2p,
        const float* __restrict__ b2, const float* __restrict__ g2,
        const float* __restrict__ be2, const float* __restrict__ m2,
        const float* __restrict__ v2, signed char* __restrict__ act2) {
    __shared__ __align__(16) signed char smem[125184];
    int tid = threadIdx.x;
    int b0 = blockIdx.x * 8;

    // linear staging: coalesced global reads, conflict-free LDS writes
    {
        const i32x4* asrc = (const i32x4*)(act1 + (size_t)b0 * 9248);
        i32x4* s4 = (i32x4*)smem;
        for (int i = tid; i < 4624; i += 768) s4[i] = asrc[i];
        const i32x4* wsrc = (const i32x4*)w2p;
        i32x4* w4 = (i32x4*)(smem + K2_WOFF);
        for (int i = tid; i < 3200; i += 768) w4[i] = wsrc[i];
    }
    __syncthreads();

    int wave = tid >> 6, lane = tid & 63;
    int lrow = lane & 31, kh = lane >> 5;
    const signed char* wbase = smem + K2_WOFF + kh * 1024 + lrow * 16;

    // per-tile fragment geometry (3 tiles per wave)
    const signed char* aimg[3];
    int pixbase[3];
#pragma unroll
    for (int t = 0; t < 3; ++t) {
        int mt = wave * 3 + t;                // 0..35
        int m = mt * 32 + lrow;
        int q = m >> 2, j = m & 3;
        int img = q / 36, qq = q - img * 36;
        int oy = 2 * (qq / 6) + (j >> 1);
        int ox = 2 * (qq - (qq / 6) * 6) + (j & 1);
        aimg[t] = smem + img * K2_IMG_STRIDE;
        pixbase[t] = oy * 17 + ox;
    }

    i32x16 acc[3][2] = {};
#pragma unroll 5
    for (int tap = 0; tap < 25; ++tap) {
        int ky = tap / 5, kx = tap - (tap / 5) * 5;
        i32x4 w0 = *(const i32x4*)(wbase + tap * 2048);        // oc = lrow
        i32x4 w1v = *(const i32x4*)(wbase + tap * 2048 + 512); // oc = 32+lrow
#pragma unroll
        for (int t = 0; t < 3; ++t) {
            int off = (pixbase[t] + ky * 17 + kx) * 32 + kh * 16;
            i32x4 a = *(const i32x4*)(aimg[t] + aswz(off));
            acc[t][0] = __builtin_amdgcn_mfma_i32_32x32x32_i8(a, w0, acc[t][0], 0, 0, 0);
            acc[t][1] = __builtin_amdgcn_mfma_i32_32x32x32_i8(a, w1v, acc[t][1], 0, 0, 0);
        }
    }

    // epilogue: BN+sign+pool (pool quad lives in reg quads of each lane)
    float bi[2], mm[2], sc[2], bb[2];
#pragma unroll
    for (int h = 0; h < 2; ++h) {
        int oc = h * 32 + lrow;
        bi[h] = b2[oc]; mm[h] = m2[oc];
        sc[h] = g2[oc] / sqrtf(v2[oc] + 1e-5f); bb[h] = be2[oc];
    }
#pragma unroll
    for (int t = 0; t < 3; ++t) {
        int mt = wave * 3 + t;
#pragma unroll
        for (int h = 0; h < 2; ++h) {
            int oc = h * 32 + lrow;
#pragma unroll
            for (int g = 0; g < 4; g++) {
                int qo = mt * 8 + kh + 2 * g;     // pool cell 0..287 (8 images)
                int imo = qo / 36, qqo = qo - imo * 36;
                float best = -2.f;
#pragma unroll
                for (int jj = 0; jj < 4; jj++) {
                    float z = (float)acc[t][h][g * 4 + jj] + bi[h];
                    float bn = (z - mm[h]) * sc[h] + bb[h];
                    best = fmaxf(best, fsign(bn));
                }
                act2[((size_t)(b0 + imo) * 64 + oc) * 36 + qqo] = (signed char)best;
            }
        }
    }
}

// K3: fc1 as LDS-tiled MFMA i8 GEMM 2048x1024x2304. (r11 verbatim)
#define K3A_SEG 2064                // 128*16 + 16 pad
#define K3B_SEG 1040                // 64*16 + 16 pad
#define K3_BOFF 16512               // 8 * 2064
__global__ __launch_bounds__(256) void k3_mfma(
        const signed char* __restrict__ act2, const signed char* __restrict__ wf1s,
        const float* __restrict__ bf1, const float* __restrict__ gf1,
        const float* __restrict__ bef1, const float* __restrict__ mf1,
        const float* __restrict__ vf1, signed char* __restrict__ act3) {
    __shared__ __align__(16) signed char s[K3_BOFF + 8 * K3B_SEG];  // 24832
    int tid = threadIdx.x;
    int bid = blockIdx.x;
    int tn = bid & 15, tm = bid >> 4;

    const signed char* Ab = act2 + (size_t)tm * 128 * 2304;
    const signed char* Bb = wf1s + (size_t)tn * 64 * 2304;
    size_t gA[4]; int lwA[4];
#pragma unroll
    for (int i = 0; i < 4; i++) {
        int e = tid + 256 * i, row = e >> 3, sg = (e + row) & 7;
        gA[i] = (size_t)row * 2304 + sg * 16;
        lwA[i] = sg * K3A_SEG + row * 16;
    }
    size_t gB[2]; int lwB[2];
#pragma unroll
    for (int i = 0; i < 2; i++) {
        int e = tid + 256 * i, row = e >> 3, sg = (e + row) & 7;
        gB[i] = (size_t)row * 2304 + sg * 16;
        lwB[i] = K3_BOFF + sg * K3B_SEG + row * 16;
    }

    i32x4 ra[4], rb[2];
#pragma unroll
    for (int i = 0; i < 4; i++) ra[i] = *(const i32x4*)(Ab + gA[i]);
#pragma unroll
    for (int i = 0; i < 2; i++) rb[i] = *(const i32x4*)(Bb + gB[i]);

    int l = tid & 63, wid = tid >> 6;
    int lrow = l & 31, kh = l >> 5;
    int raddrA = kh * K3A_SEG + (wid * 32 + lrow) * 16;
    int raddrB0 = K3_BOFF + kh * K3B_SEG + lrow * 16;
    int raddrB1 = raddrB0 + 32 * 16;

    i32x16 acc0 = {0};
    i32x16 acc1 = {0};
    for (int t = 0; t < 18; ++t) {
        if (t) __syncthreads();
#pragma unroll
        for (int i = 0; i < 4; i++) *(i32x4*)(s + lwA[i]) = ra[i];
#pragma unroll
        for (int i = 0; i < 2; i++) *(i32x4*)(s + lwB[i]) = rb[i];
        if (t < 17) {
            size_t ko = (size_t)(t + 1) * 128;
#pragma unroll
            for (int i = 0; i < 4; i++) ra[i] = *(const i32x4*)(Ab + gA[i] + ko);
#pragma unroll
            for (int i = 0; i < 2; i++) rb[i] = *(const i32x4*)(Bb + gB[i] + ko);
        }
        __syncthreads();
#pragma unroll
        for (int ks = 0; ks < 4; ++ks) {
            i32x4 a  = *(const i32x4*)(s + raddrA + ks * 2 * K3A_SEG);
            i32x4 b0 = *(const i32x4*)(s + raddrB0 + ks * 2 * K3B_SEG);
            i32x4 b1 = *(const i32x4*)(s + raddrB1 + ks * 2 * K3B_SEG);
            acc0 = __builtin_amdgcn_mfma_i32_32x32x32_i8(a, b0, acc0, 0, 0, 0);
            acc1 = __builtin_amdgcn_mfma_i32_32x32x32_i8(a, b1, acc1, 0, 0, 0);
        }
    }

    int col0 = tn * 64 + lrow;
    int col1 = col0 + 32;
    float bi0 = bf1[col0], m0 = mf1[col0];
    float sc0 = gf1[col0] / sqrtf(vf1[col0] + 1e-5f), bb0 = bef1[col0];
    float bi1 = bf1[col1], m1 = mf1[col1];
    float sc1 = gf1[col1] / sqrtf(vf1[col1] + 1e-5f), bb1 = bef1[col1];
#pragma unroll
    for (int r = 0; r < 16; r++) {
        int row = tm * 128 + wid * 32 + (r & 3) + 8 * (r >> 2) + 4 * kh;
        float bn0 = ((float)acc0[r] + bi0 - m0) * sc0 + bb0;
        float bn1 = ((float)acc1[r] + bi1 - m1) * sc1 + bb1;
        act3[(size_t)row * 1024 + col0] = (signed char)fsign(bn0);
        act3[(size_t)row * 1024 + col1] = (signed char)fsign(bn1);
    }
}

// K4: fc2 (1024->10) + bias + BN + log_softmax. One wave per image. (r11 verbatim)
__global__ void k4_fc2(const signed char* __restrict__ act3, const signed char* __restrict__ swf2,
                       const float* __restrict__ bf2, const float* __restrict__ gf2,
                       const float* __restrict__ bef2, const float* __restrict__ mf2,
                       const float* __restrict__ vf2, float* __restrict__ out) {
    int wid = (blockIdx.x * 256 + threadIdx.x) >> 6;
    int lane = threadIdx.x & 63;
    if (wid >= BATCH) return;
    const int* hd = (const int*)act3 + (size_t)wid * 256;
    const int* wd = (const int*)swf2;
    int acc[10];
#pragma unroll
    for (int o = 0; o < 10; o++) acc[o] = 0;
#pragma unroll
    for (int i = 0; i < 4; i++) {
        int k4 = i * 64 + lane;
        int hv = hd[k4];
#pragma unroll
        for (int o = 0; o < 10; o++)
            acc[o] = sdot4(hv, wd[o * 256 + k4], acc[o]);
    }
#pragma unroll
    for (int o = 0; o < 10; o++)
#pragma unroll
        for (int s = 32; s > 0; s >>= 1) acc[o] += __shfl_xor(acc[o], s);
    if (lane == 0) {
        float logit[10];
        float mx = -1e30f;
#pragma unroll
        for (int o = 0; o < 10; o++) {
            float z = (float)acc[o] + bf2[o];
            float bn = (z - mf2[o]) * (gf2[o] / sqrtf(vf2[o] + 1e-5f)) + bef2[o];
            logit[o] = bn;
            mx = fmaxf(mx, bn);
        }
        float s = 0.f;
#pragma unroll
        for (int o = 0; o < 10; o++) s += expf(logit[o] - mx);
        float lse = mx + logf(s);
#pragma unroll
        for (int o = 0; o < 10; o++) out[(size_t)wid * 10 + o] = logit[o] - lse;
    }
}

extern "C" void kernel_launch(void* const* d_in, const int* in_sizes, int n_in,
                              void* d_out, int out_size, void* d_ws, size_t ws_size,
                              hipStream_t stream) {
    const float* x   = (const float*)d_in[0];
    const float* w1  = (const float*)d_in[1];
    const float* b1  = (const float*)d_in[2];
    const float* g1  = (const float*)d_in[3];
    const float* be1 = (const float*)d_in[4];
    const float* m1  = (const float*)d_in[5];
    const float* v1  = (const float*)d_in[6];
    const float* w2  = (const float*)d_in[7];
    const float* b2  = (const float*)d_in[8];
    const float* g2  = (const float*)d_in[9];
    const float* be2 = (const float*)d_in[10];
    const float* m2  = (const float*)d_in[11];
    const float* v2  = (const float*)d_in[12];
    const float* wf1 = (const float*)d_in[13];
    const float* bf1 = (const float*)d_in[14];
    const float* gf1 = (const float*)d_in[15];
    const float* bef1= (const float*)d_in[16];
    const float* mf1 = (const float*)d_in[17];
    const float* vf1 = (const float*)d_in[18];
    const float* wf2 = (const float*)d_in[19];
    const float* bf2 = (const float*)d_in[20];
    const float* gf2 = (const float*)d_in[21];
    const float* bef2= (const float*)d_in[22];
    const float* mf2 = (const float*)d_in[23];
    const float* vf2 = (const float*)d_in[24];
    float* out = (float*)d_out;

    // ws layout (all int8 unless noted)
    char* ws = (char*)d_ws;
    signed char* act1 = (signed char*)ws;                  // 2048*9248     = 18,939,904
    signed char* act2 = act1 + 18939904;                   // 2048*2304     =  4,718,592
    signed char* act3 = act2 + 4718592;                    // 2048*1024     =  2,097,152
    signed char* w2p  = act3 + 2097152;                    // 25*2*64*16    =     51,200
    signed char* wf1s = w2p + 51200;                       // 1024*2304     =  2,359,296
    signed char* wf2p = wf1s + 2359296;                    // 10*1024       =     10,240
    float* k1c = (float*)(wf2p + 10240);                   // 32*16 floats  =      2,048 B

    // prep: 2,359,296 + 51,200 + 10,240 + 416 = 2,421,152 elems -> 9458 blocks
    prep_all<<<9458, 256, 0, stream>>>(w1, b1, g1, be1, m1, v1, w2, wf1, wf2,
                                       w2p, wf1s, wf2p, k1c);

    k1_conv1<<<2048, 256, 0, stream>>>(x, k1c, act1);

    k2_mfma<<<256, 768, 0, stream>>>(act1, w2p, b2, g2, be2, m2, v2, act2);

    k3_mfma<<<256, 256, 0, stream>>>(act2, wf1s, bf1, gf1, bef1, mf1, vf1, act3);

    k4_fc2<<<512, 256, 0, stream>>>(act3, wf2p, bf2, gf2, bef2, mf2, vf2, out);
}

// Round 20
// 76.034 us; speedup vs baseline: 1.2881x; 1.0036x over previous
//
#include <hip/hip_runtime.h>
#include <math.h>

#define BATCH 2048

typedef __attribute__((ext_vector_type(4))) int i32x4;
typedef __attribute__((ext_vector_type(16))) int i32x16;

__device__ __forceinline__ int sdot4(int a, int b, int c) {
    return __builtin_amdgcn_sdot4(a, b, c, false);
}

__device__ __forceinline__ float fsign(float v) {
    return v > 0.f ? 1.f : (v < 0.f ? -1.f : 0.f);
}

// act swizzle (T2): flips addr bits 4-6 by pixel bits 2-4; bijective on [0,9248),
// keeps 16B chunks intact, independent of the low 5 bits (oc).
__device__ __forceinline__ int aswz(int off) {
    return off ^ (((off >> 7) & 7) << 4);
}

// Fused prep: wf1 binarize | w2 pack [tap][half][oc][16] | wf2 binarize | k1c table
__global__ void prep_all(const float* __restrict__ w1, const float* __restrict__ b1,
                         const float* __restrict__ g1, const float* __restrict__ be1,
                         const float* __restrict__ m1, const float* __restrict__ v1,
                         const float* __restrict__ w2, const float* __restrict__ wf1,
                         const float* __restrict__ wf2,
                         signed char* __restrict__ w2p, signed char* __restrict__ wf1s,
                         signed char* __restrict__ wf2p, float* __restrict__ k1c) {
    int i = blockIdx.x * 256 + threadIdx.x;
    if (i < 2359296) {  // wf1 sign (natural [1024][2304] layout)
        float v = wf1[i];
        wf1s[i] = v > 0.f ? 1 : (v < 0.f ? -1 : 0);
        return;
    }
    i -= 2359296;
    if (i < 51200) {    // w2 [64][32][5][5] -> w2p [25 tap][2 khalf][64 oc][16 ic]
        int tap = i >> 11;
        int r = i & 2047;
        int half = r >> 10;
        int r2 = r & 1023;
        int oc = r2 >> 4, j = r2 & 15;
        int ic = half * 16 + j;
        float v = w2[(oc * 32 + ic) * 25 + tap];
        w2p[i] = v > 0.f ? 1 : (v < 0.f ? -1 : 0);
        return;
    }
    i -= 51200;
    if (i < 10240) {    // wf2 sign
        float v = wf2[i];
        wf2p[i] = v > 0.f ? 1 : (v < 0.f ? -1 : 0);
        return;
    }
    i -= 10240;
    if (i < 416) {      // k1c [32][16] = {sw0..8, bias, m, sc, bb}
        int oc = i / 13, s = i - oc * 13;
        float r;
        if (s < 9) r = fsign(w1[oc * 9 + s]);
        else if (s == 9) r = b1[oc];
        else if (s == 10) r = m1[oc];
        else if (s == 11) r = g1[oc] / sqrtf(v1[oc] + 1e-5f);
        else r = be1[oc];
        k1c[oc * 16 + s] = r;
    }
}

// K1: conv1 + bias + BN + sign + pool2 -> act1 in k2's padded+swizzled layout.
__global__ __launch_bounds__(256) void k1_conv1(
        const float* __restrict__ x, const float* __restrict__ k1c,
        signed char* __restrict__ act1) {
    __shared__ __align__(16) float xs[784];
    __shared__ __align__(16) float xs2[784];   // xs2[i] = xs[i+2]
    int b = blockIdx.x, tid = threadIdx.x;
    if (tid < 196) ((float4*)xs)[tid] = ((const float4*)(x + (size_t)b * 784))[tid];
    __syncthreads();
    for (int j = tid; j < 782; j += 256) xs2[j] = xs[j + 2];

    signed char* img = act1 + (size_t)b * 9248;
    // zero the 120 border pixels (240 x 16B chunks)
    i32x4 z4 = {0, 0, 0, 0};
    for (int i = tid; i < 240; i += 256) {
        int pi = i >> 1, half = i & 1;
        int p;
        if (pi < 34) p = pi;                       // rows 0-1
        else if (pi < 68) p = 255 + (pi - 34);     // rows 15-16
        else {                                     // rows 2-14, cols 0,1,15,16
            int j2 = pi - 68;
            int row = 2 + (j2 >> 2), c = j2 & 3;
            int col = (c < 2) ? c : 13 + c;        // 0,1,15,16
            p = row * 17 + col;
        }
        *(i32x4*)(img + aswz(p * 32 + half * 16)) = z4;
    }
    __syncthreads();

    int oc = tid & 31, g = tid >> 5;
    const float* c = k1c + oc * 16;
    float sw[9];
#pragma unroll
    for (int i = 0; i < 9; i++) sw[i] = c[i];
    float bias = c[9], m = c[10], sc = c[11], bb = c[12];

    for (int i = 0; i < 22; i++) {
        int cell = i * 8 + g;
        if (cell < 169) {
            int py = cell / 13, px = cell - py * 13;
            const float* wnd = (px & 1) ? (xs2 + py * 56 + px * 2 - 2)
                                        : (xs + py * 56 + px * 2);
            float xr[4][4];
#pragma unroll
            for (int dy = 0; dy < 4; dy++) {
                float4 rv = *(const float4*)(wnd + dy * 28);   // aligned b128
                xr[dy][0] = rv.x; xr[dy][1] = rv.y;
                xr[dy][2] = rv.z; xr[dy][3] = rv.w;
            }
            float maxacc = -1e30f;
#pragma unroll
            for (int q = 0; q < 4; q++) {
                int dyp = q >> 1, dxp = q & 1;
                float acc = 0.f;
#pragma unroll
                for (int ky = 0; ky < 3; ky++)
#pragma unroll
                    for (int kx = 0; kx < 3; kx++)
                        acc += xr[dyp + ky][dxp + kx] * sw[ky * 3 + kx];
                maxacc = fmaxf(maxacc, acc);   // BN monotone (sc>0): max commutes
            }
            float bn = (maxacc + bias - m) * sc + bb;  // same assoc as before
            int p32 = ((py + 2) * 17 + (px + 2)) * 32;
            img[aswz(p32 + oc)] = (signed char)fsign(bn);
        }
    }
}

// K2: conv2 implicit-GEMM MFMA i8. Block = 8 images, 12 waves (768 thr).
// Grid = 256 = 1 block/CU. Epilogue now goes THROUGH LDS: sign bytes staged
// as [img][oc][36] in the dead act region, then linear coalesced copy-out.
#define K2_IMG_STRIDE 9248          // 17*17*32
#define K2_WOFF 73984               // 8*9248
__global__ __launch_bounds__(768) void k2_mfma(
        const signed char* __restrict__ act1, const signed char* __restrict__ w2p,
        const float* __restrict__ b2, const float* __restrict__ g2,
        const float* __restrict__ be2, const float* __restrict__ m2,
        const float* __restrict__ v2, signed char* __restrict__ act2) {
    __shared__ __align__(16) signed char smem[125184];
    int tid = threadIdx.x;
    int b0 = blockIdx.x * 8;

    // linear staging: coalesced global reads, conflict-free LDS writes
    {
        const i32x4* asrc = (const i32x4*)(act1 + (size_t)b0 * 9248);
        i32x4* s4 = (i32x4*)smem;
        for (int i = tid; i < 4624; i += 768) s4[i] = asrc[i];
        const i32x4* wsrc = (const i32x4*)w2p;
        i32x4* w4 = (i32x4*)(smem + K2_WOFF);
        for (int i = tid; i < 3200; i += 768) w4[i] = wsrc[i];
    }
    __syncthreads();

    int wave = tid >> 6, lane = tid & 63;
    int lrow = lane & 31, kh = lane >> 5;
    const signed char* wbase = smem + K2_WOFF + kh * 1024 + lrow * 16;

    // per-tile fragment geometry (3 tiles per wave)
    const signed char* aimg[3];
    int pixbase[3];
#pragma unroll
    for (int t = 0; t < 3; ++t) {
        int mt = wave * 3 + t;                // 0..35
        int m = mt * 32 + lrow;
        int q = m >> 2, j = m & 3;
        int img = q / 36, qq = q - img * 36;
        int oy = 2 * (qq / 6) + (j >> 1);
        int ox = 2 * (qq - (qq / 6) * 6) + (j & 1);
        aimg[t] = smem + img * K2_IMG_STRIDE;
        pixbase[t] = oy * 17 + ox;
    }

    i32x16 acc[3][2] = {};
#pragma unroll 5
    for (int tap = 0; tap < 25; ++tap) {
        int ky = tap / 5, kx = tap - (tap / 5) * 5;
        i32x4 w0 = *(const i32x4*)(wbase + tap * 2048);        // oc = lrow
        i32x4 w1v = *(const i32x4*)(wbase + tap * 2048 + 512); // oc = 32+lrow
#pragma unroll
        for (int t = 0; t < 3; ++t) {
            int off = (pixbase[t] + ky * 17 + kx) * 32 + kh * 16;
            i32x4 a = *(const i32x4*)(aimg[t] + aswz(off));
            acc[t][0] = __builtin_amdgcn_mfma_i32_32x32x32_i8(a, w0, acc[t][0], 0, 0, 0);
            acc[t][1] = __builtin_amdgcn_mfma_i32_32x32x32_i8(a, w1v, acc[t][1], 0, 0, 0);
        }
    }
    __syncthreads();   // all LDS A/W reads done -> act region reusable

    // epilogue: BN+sign+pool -> LDS [img][oc][36] (stride-36 bytes: bank-clean)
    float bi[2], mm[2], sc[2], bb[2];
#pragma unroll
    for (int h = 0; h < 2; ++h) {
        int oc = h * 32 + lrow;
        bi[h] = b2[oc]; mm[h] = m2[oc];
        sc[h] = g2[oc] / sqrtf(v2[oc] + 1e-5f); bb[h] = be2[oc];
    }
#pragma unroll
    for (int t = 0; t < 3; ++t) {
        int mt = wave * 3 + t;
#pragma unroll
        for (int h = 0; h < 2; ++h) {
            int oc = h * 32 + lrow;
#pragma unroll
            for (int g = 0; g < 4; g++) {
                int qo = mt * 8 + kh + 2 * g;     // pool cell 0..287 (8 images)
                int imo = qo / 36, qqo = qo - imo * 36;
                float best = -2.f;
#pragma unroll
                for (int jj = 0; jj < 4; jj++) {
                    float z = (float)acc[t][h][g * 4 + jj] + bi[h];
                    float bn = (z - mm[h]) * sc[h] + bb[h];
                    best = fmaxf(best, fsign(bn));
                }
                smem[imo * 2304 + oc * 36 + qqo] = (signed char)best;
            }
        }
    }
    __syncthreads();

    // coalesced copy-out: 18,432 B linear (matches act2 [b][64][36])
    {
        const i32x4* s4o = (const i32x4*)smem;
        i32x4* dst = (i32x4*)(act2 + (size_t)b0 * 2304);
        for (int i = tid; i < 1152; i += 768) dst[i] = s4o[i];
    }
}

// K3: fc1 as LDS-tiled MFMA i8 GEMM 2048x1024x2304.
// Epilogue now stages the 128x64 tile in LDS, then 64B-contiguous stores.
#define K3A_SEG 2064                // 128*16 + 16 pad
#define K3B_SEG 1040                // 64*16 + 16 pad
#define K3_BOFF 16512               // 8 * 2064
__global__ __launch_bounds__(256) void k3_mfma(
        const signed char* __restrict__ act2, const signed char* __restrict__ wf1s,
        const float* __restrict__ bf1, const float* __restrict__ gf1,
        const float* __restrict__ bef1, const float* __restrict__ mf1,
        const float* __restrict__ vf1, signed char* __restrict__ act3) {
    __shared__ __align__(16) signed char s[K3_BOFF + 8 * K3B_SEG];  // 24832
    int tid = threadIdx.x;
    int bid = blockIdx.x;
    int tn = bid & 15, tm = bid >> 4;

    const signed char* Ab = act2 + (size_t)tm * 128 * 2304;
    const signed char* Bb = wf1s + (size_t)tn * 64 * 2304;
    size_t gA[4]; int lwA[4];
#pragma unroll
    for (int i = 0; i < 4; i++) {
        int e = tid + 256 * i, row = e >> 3, sg = (e + row) & 7;
        gA[i] = (size_t)row * 2304 + sg * 16;
        lwA[i] = sg * K3A_SEG + row * 16;
    }
    size_t gB[2]; int lwB[2];
#pragma unroll
    for (int i = 0; i < 2; i++) {
        int e = tid + 256 * i, row = e >> 3, sg = (e + row) & 7;
        gB[i] = (size_t)row * 2304 + sg * 16;
        lwB[i] = K3_BOFF + sg * K3B_SEG + row * 16;
    }

    i32x4 ra[4], rb[2];
#pragma unroll
    for (int i = 0; i < 4; i++) ra[i] = *(const i32x4*)(Ab + gA[i]);
#pragma unroll
    for (int i = 0; i < 2; i++) rb[i] = *(const i32x4*)(Bb + gB[i]);

    int l = tid & 63, wid = tid >> 6;
    int lrow = l & 31, kh = l >> 5;
    int raddrA = kh * K3A_SEG + (wid * 32 + lrow) * 16;
    int raddrB0 = K3_BOFF + kh * K3B_SEG + lrow * 16;
    int raddrB1 = raddrB0 + 32 * 16;

    i32x16 acc0 = {0};
    i32x16 acc1 = {0};
    for (int t = 0; t < 18; ++t) {
        if (t) __syncthreads();
#pragma unroll
        for (int i = 0; i < 4; i++) *(i32x4*)(s + lwA[i]) = ra[i];
#pragma unroll
        for (int i = 0; i < 2; i++) *(i32x4*)(s + lwB[i]) = rb[i];
        if (t < 17) {
            size_t ko = (size_t)(t + 1) * 128;
#pragma unroll
            for (int i = 0; i < 4; i++) ra[i] = *(const i32x4*)(Ab + gA[i] + ko);
#pragma unroll
            for (int i = 0; i < 2; i++) rb[i] = *(const i32x4*)(Bb + gB[i] + ko);
        }
        __syncthreads();
#pragma unroll
        for (int ks = 0; ks < 4; ++ks) {
            i32x4 a  = *(const i32x4*)(s + raddrA + ks * 2 * K3A_SEG);
            i32x4 b0 = *(const i32x4*)(s + raddrB0 + ks * 2 * K3B_SEG);
            i32x4 b1 = *(const i32x4*)(s + raddrB1 + ks * 2 * K3B_SEG);
            acc0 = __builtin_amdgcn_mfma_i32_32x32x32_i8(a, b0, acc0, 0, 0, 0);
            acc1 = __builtin_amdgcn_mfma_i32_32x32x32_i8(a, b1, acc1, 0, 0, 0);
        }
    }

    int col0 = tn * 64 + lrow;
    int col1 = col0 + 32;
    float bi0 = bf1[col0], m0 = mf1[col0];
    float sc0 = gf1[col0] / sqrtf(vf1[col0] + 1e-5f), bb0 = bef1[col0];
    float bi1 = bf1[col1], m1 = mf1[col1];
    float sc1 = gf1[col1] / sqrtf(vf1[col1] + 1e-5f), bb1 = bef1[col1];
    __syncthreads();   // K-loop reads of s done -> reuse as output tile [128][64]
#pragma unroll
    for (int r = 0; r < 16; r++) {
        int rowl = wid * 32 + (r & 3) + 8 * (r >> 2) + 4 * kh;
        float bn0 = ((float)acc0[r] + bi0 - m0) * sc0 + bb0;
        float bn1 = ((float)acc1[r] + bi1 - m1) * sc1 + bb1;
        s[rowl * 64 + lrow] = (signed char)fsign(bn0);
        s[rowl * 64 + lrow + 32] = (signed char)fsign(bn1);
    }
    __syncthreads();
    // coalesced out: each row's 64B is contiguous in global (act3 row stride 1024)
    for (int i = tid; i < 512; i += 256) {
        int rl = i >> 2, c16 = i & 3;
        *(i32x4*)(act3 + (size_t)(tm * 128 + rl) * 1024 + tn * 64 + c16 * 16) =
            *(const i32x4*)(s + i * 16);
    }
}

// K4: fc2 (1024->10) + bias + BN + log_softmax. One wave per image. (unchanged)
__global__ void k4_fc2(const signed char* __restrict__ act3, const signed char* __restrict__ swf2,
                       const float* __restrict__ bf2, const float* __restrict__ gf2,
                       const float* __restrict__ bef2, const float* __restrict__ mf2,
                       const float* __restrict__ vf2, float* __restrict__ out) {
    int wid = (blockIdx.x * 256 + threadIdx.x) >> 6;
    int lane = threadIdx.x & 63;
    if (wid >= BATCH) return;
    const int* hd = (const int*)act3 + (size_t)wid * 256;
    const int* wd = (const int*)swf2;
    int acc[10];
#pragma unroll
    for (int o = 0; o < 10; o++) acc[o] = 0;
#pragma unroll
    for (int i = 0; i < 4; i++) {
        int k4 = i * 64 + lane;
        int hv = hd[k4];
#pragma unroll
        for (int o = 0; o < 10; o++)
            acc[o] = sdot4(hv, wd[o * 256 + k4], acc[o]);
    }
#pragma unroll
    for (int o = 0; o < 10; o++)
#pragma unroll
        for (int s = 32; s > 0; s >>= 1) acc[o] += __shfl_xor(acc[o], s);
    if (lane == 0) {
        float logit[10];
        float mx = -1e30f;
#pragma unroll
        for (int o = 0; o < 10; o++) {
            float z = (float)acc[o] + bf2[o];
            float bn = (z - mf2[o]) * (gf2[o] / sqrtf(vf2[o] + 1e-5f)) + bef2[o];
            logit[o] = bn;
            mx = fmaxf(mx, bn);
        }
        float s = 0.f;
#pragma unroll
        for (int o = 0; o < 10; o++) s += expf(logit[o] - mx);
        float lse = mx + logf(s);
#pragma unroll
        for (int o = 0; o < 10; o++) out[(size_t)wid * 10 + o] = logit[o] - lse;
    }
}

extern "C" void kernel_launch(void* const* d_in, const int* in_sizes, int n_in,
                              void* d_out, int out_size, void* d_ws, size_t ws_size,
                              hipStream_t stream) {
    const float* x   = (const float*)d_in[0];
    const float* w1  = (const float*)d_in[1];
    const float* b1  = (const float*)d_in[2];
    const float* g1  = (const float*)d_in[3];
    const float* be1 = (const float*)d_in[4];
    const float* m1  = (const float*)d_in[5];
    const float* v1  = (const float*)d_in[6];
    const float* w2  = (const float*)d_in[7];
    const float* b2  = (const float*)d_in[8];
    const float* g2  = (const float*)d_in[9];
    const float* be2 = (const float*)d_in[10];
    const float* m2  = (const float*)d_in[11];
    const float* v2  = (const float*)d_in[12];
    const float* wf1 = (const float*)d_in[13];
    const float* bf1 = (const float*)d_in[14];
    const float* gf1 = (const float*)d_in[15];
    const float* bef1= (const float*)d_in[16];
    const float* mf1 = (const float*)d_in[17];
    const float* vf1 = (const float*)d_in[18];
    const float* wf2 = (const float*)d_in[19];
    const float* bf2 = (const float*)d_in[20];
    const float* gf2 = (const float*)d_in[21];
    const float* bef2= (const float*)d_in[22];
    const float* mf2 = (const float*)d_in[23];
    const float* vf2 = (const float*)d_in[24];
    float* out = (float*)d_out;

    // ws layout (all int8 unless noted)
    char* ws = (char*)d_ws;
    signed char* act1 = (signed char*)ws;                  // 2048*9248     = 18,939,904
    signed char* act2 = act1 + 18939904;                   // 2048*2304     =  4,718,592
    signed char* act3 = act2 + 4718592;                    // 2048*1024     =  2,097,152
    signed char* w2p  = act3 + 2097152;                    // 25*2*64*16    =     51,200
    signed char* wf1s = w2p + 51200;                       // 1024*2304     =  2,359,296
    signed char* wf2p = wf1s + 2359296;                    // 10*1024       =     10,240
    float* k1c = (float*)(wf2p + 10240);                   // 32*16 floats  =      2,048 B

    // prep: 2,359,296 + 51,200 + 10,240 + 416 = 2,421,152 elems -> 9458 blocks
    prep_all<<<9458, 256, 0, stream>>>(w1, b1, g1, be1, m1, v1, w2, wf1, wf2,
                                       w2p, wf1s, wf2p, k1c);

    k1_conv1<<<2048, 256, 0, stream>>>(x, k1c, act1);

    k2_mfma<<<256, 768, 0, stream>>>(act1, w2p, b2, g2, be2, m2, v2, act2);

    k3_mfma<<<256, 256, 0, stream>>>(act2, wf1s, bf1, gf1, bef1, mf1, vf1, act3);

    k4_fc2<<<512, 256, 0, stream>>>(act3, wf2p, bf2, gf2, bef2, mf2, vf2, out);
}